// Round 7
// baseline (730.191 us; speedup 1.0000x reference)
//
#include <hip/hip_runtime.h>

#define BB 8
#define VV 1200
#define DD 64
#define KH 2     // hops
#define NH 4     // heads
#define CAP 64        // hop1 cap
#define NB2CAP 384    // hop2 cap
#define NROW (BB*VV)          // 9600
#define NKROW (KH*BB*VV)      // 19200

__device__ __forceinline__ float wredsum(float v) {
#pragma unroll
  for (int o = 32; o > 0; o >>= 1) v += __shfl_xor(v, o, 64);
  return v;
}
// reduce within 32-lane half-wave
__device__ __forceinline__ float hredsum(float v) {
#pragma unroll
  for (int o = 16; o > 0; o >>= 1) v += __shfl_xor(v, o, 64);
  return v;
}

// fast tanh via hw exp: tanh(x) = 1 - 2/(e^{2x}+1)
__device__ __forceinline__ float tanh_f(float x) {
  float e = __expf(2.0f * x);
  return 1.0f - 2.0f / (e + 1.0f);
}
__device__ __forceinline__ float sigmoid_f(float x) { return 1.0f / (1.0f + __expf(-x)); }

__device__ __forceinline__ size_t nb_base(int row) {
  return (row < NROW) ? (size_t)row * CAP
                      : (size_t)NROW * CAP + (size_t)(row - NROW) * NB2CAP;
}

// ---------------- build CSR of binary neighborhoods (dense 92MB read once) ----------------
__global__ void __launch_bounds__(256) k_nbcsr(
    const float* __restrict__ nb,
    int* __restrict__ nb_cols, int* __restrict__ nb_cnt) {
  int wid = threadIdx.x >> 6, lane = threadIdx.x & 63;
  int row = blockIdx.x * 4 + wid;
  if (row >= NKROW) return;
  const float* nbrow = nb + (size_t)row * VV;
  size_t base = nb_base(row);
  int cap = (row < NROW) ? CAP : NB2CAP;
  unsigned long long ltmask = (lane == 0) ? 0ull : ((1ull << lane) - 1ull);
  int cnt = 0;
  for (int b0 = 0; b0 < VV; b0 += 64) {
    int v = b0 + lane;
    float val = (v < VV) ? nbrow[v] : 0.0f;
    unsigned long long mask = __ballot(val != 0.0f);
    int off = cnt + __popcll(mask & ltmask);
    if (val != 0.0f && off < cap) nb_cols[base + off] = v;
    cnt += __popcll(mask);
  }
  if (lane == 0) nb_cnt[row] = (cnt > cap) ? cap : cnt;
}

// ---------------- encoder: 8 rows/block, thread=(row, col-pair) ----------------
__global__ void __launch_bounds__(256) k_encoder(
    const float* __restrict__ emb, const float* __restrict__ feat,
    const float* __restrict__ w0, const float* __restrict__ b0,
    const float* __restrict__ w1, const float* __restrict__ b1,
    float* __restrict__ enc0) {
  __shared__ float xT[8][25];
  __shared__ float hT[8][65];
  int tid = threadIdx.x;
  int tile0 = blockIdx.x * 8;
  if (tid < 128) { int i = tid >> 4, d = tid & 15; xT[i][d] = emb[(size_t)(tile0 + i) * 16 + d]; }
  else if (tid < 192) { int t = tid - 128; int i = t >> 3, d = t & 7; xT[i][16 + d] = feat[(size_t)(tile0 + i) * 8 + d]; }
  __syncthreads();
  int r = tid >> 5, cg = tid & 31;
  int c0 = cg * 2;
  float a0 = b0[c0], a1 = b0[c0 + 1];
#pragma unroll
  for (int kk = 0; kk < 24; ++kk) {
    float x = xT[r][kk];
    float2 w2 = *(const float2*)(w0 + kk * DD + c0);
    a0 = fmaf(x, w2.x, a0); a1 = fmaf(x, w2.y, a1);
  }
  hT[r][c0] = tanh_f(a0); hT[r][c0 + 1] = tanh_f(a1);
  __syncthreads();
  float g0 = b1[c0], g1 = b1[c0 + 1];
#pragma unroll 16
  for (int kk = 0; kk < DD; ++kk) {
    float x = hT[r][kk];
    float2 w2 = *(const float2*)(w1 + kk * DD + c0);
    g0 = fmaf(x, w2.x, g0); g1 = fmaf(x, w2.y, g1);
  }
  float2 o; o.x = tanh_f(g0); o.y = tanh_f(g1);
  *(float2*)(enc0 + (size_t)(tile0 + r) * DD + c0) = o;
}

// ---------------- gather: wave per row, float4 lanes, deep ILP ----------------
__global__ void __launch_bounds__(256) k_gather(
    const int* __restrict__ nb_cols, const int* __restrict__ nb_cnt,
    const float* __restrict__ encIn, float* __restrict__ msg) {
  int w = threadIdx.x >> 6, lane = threadIdx.x & 63;
  int row = blockIdx.x * 4 + w;           // [0, NKROW)
  int k = (row >= NROW) ? 1 : 0;
  int bv = row - k * NROW;
  int b = bv / VV;
  const float4* enc4 = (const float4*)(encIn + (size_t)b * VV * DD);
  const int* cols = nb_cols + nb_base(row);
  int n = nb_cnt[row];
  int sub = lane >> 4, q = lane & 15;
  float ax = 0.0f, ay = 0.0f, az = 0.0f, aw = 0.0f;
  int j = 0;
  for (; j + 16 <= n; j += 16) {
    int c0 = cols[j + sub];
    int c1 = cols[j + 4 + sub];
    int c2 = cols[j + 8 + sub];
    int c3 = cols[j + 12 + sub];
    float4 v0 = enc4[(size_t)c0 * 16 + q];
    float4 v1 = enc4[(size_t)c1 * 16 + q];
    float4 v2 = enc4[(size_t)c2 * 16 + q];
    float4 v3 = enc4[(size_t)c3 * 16 + q];
    ax += (v0.x + v1.x) + (v2.x + v3.x);
    ay += (v0.y + v1.y) + (v2.y + v3.y);
    az += (v0.z + v1.z) + (v2.z + v3.z);
    aw += (v0.w + v1.w) + (v2.w + v3.w);
  }
  for (; j < n; j += 4) {
    int idx = j + sub;
    if (idx < n) {
      float4 v = enc4[(size_t)cols[idx] * 16 + q];
      ax += v.x; ay += v.y; az += v.z; aw += v.w;
    }
  }
#pragma unroll
  for (int o = 16; o < 64; o <<= 1) {
    ax += __shfl_xor(ax, o, 64);
    ay += __shfl_xor(ay, o, 64);
    az += __shfl_xor(az, o, 64);
    aw += __shfl_xor(aw, o, 64);
  }
  if (lane < 16) {
    float inv = 1.0f / fmaxf((float)n, 1.0f);
    float4 r; r.x = ax * inv; r.y = ay * inv; r.z = az * inv; r.w = aw * inv;
    ((float4*)(msg + (size_t)row * DD))[q] = r;
  }
}

// ---------------- agg GEMM + attention scores: 8 rows/block, slim threads ----------------
__global__ void __launch_bounds__(256) k_aggatt(
    const float* __restrict__ msg,
    const float* __restrict__ agg_w, const float* __restrict__ agg_b,
    const float* __restrict__ att_w, const float* __restrict__ att_b,
    const float* __restrict__ att_v,
    float* __restrict__ agg, float* __restrict__ scores) {
  __shared__ float M[8][65];
  __shared__ float G[8][65];
  int tid = threadIdx.x;
  int tile0 = blockIdx.x * 8;             // [0, NKROW)
  int k = (tile0 >= NROW) ? 1 : 0;
  int bv0 = tile0 - k * NROW;
  int r = tid >> 5, cg = tid & 31;
  int c0 = cg * 2;
  int row = tile0 + r;
  {
    float2 m2 = *(const float2*)(msg + (size_t)row * DD + c0);
    M[r][c0] = m2.x; M[r][c0 + 1] = m2.y;
  }
  __syncthreads();
  const float* W = agg_w + (size_t)k * DD * DD;
  float a0 = agg_b[k * DD + c0], a1 = agg_b[k * DD + c0 + 1];
#pragma unroll 16
  for (int kk = 0; kk < DD; ++kk) {
    float x = M[r][kk];
    float2 w2 = *(const float2*)(W + kk * DD + c0);
    a0 = fmaf(x, w2.x, a0); a1 = fmaf(x, w2.y, a1);
  }
  float2 g2; g2.x = tanh_f(a0); g2.y = tanh_f(a1);
  *(float2*)(agg + (size_t)row * DD + c0) = g2;
  G[r][c0] = g2.x; G[r][c0 + 1] = g2.y;
  __syncthreads();
#pragma unroll
  for (int h = 0; h < NH; ++h) {
    const float* Wh = att_w + (size_t)h * DD * DD;
    float p0 = att_b[h * DD + c0], p1 = att_b[h * DD + c0 + 1];
#pragma unroll 16
    for (int kk = 0; kk < DD; ++kk) {
      float x = G[r][kk];
      float2 w2 = *(const float2*)(Wh + kk * DD + c0);
      p0 = fmaf(x, w2.x, p0); p1 = fmaf(x, w2.y, p1);
    }
    float2 v2 = *(const float2*)(att_v + h * DD + c0);
    float p = tanh_f(p0) * v2.x + tanh_f(p1) * v2.y;
    p = hredsum(p);
    if (cg == 0) scores[(size_t)(h * KH + k) * NROW + bv0 + r] = p;
  }
}

// ---------------- attention mix + GRU (+ fused decode), 8 rows/block, slim ----------------
__global__ void __launch_bounds__(256) k_gru(
    const float* __restrict__ encIn, const float* __restrict__ agg,
    const float* __restrict__ scores,
    const float* __restrict__ wu, const float* __restrict__ bu,
    const float* __restrict__ wr, const float* __restrict__ br,
    const float* __restrict__ wc, const float* __restrict__ bc,
    float* __restrict__ encOut,
    int do_decode,
    const float* __restrict__ dw0, const float* __restrict__ db0,
    const float* __restrict__ dw1, const float* __restrict__ db1,
    const float* __restrict__ uw0, const float* __restrict__ ub0,
    const float* __restrict__ uw1, const float* __restrict__ ub1,
    float* __restrict__ pred, float* __restrict__ dualp) {
  __shared__ float X[8][130];      // [row][0..63]=nxt, [64..127]=enc then r*enc
  int tid = threadIdx.x;
  int tile0 = blockIdx.x * 8;
  int r = tid >> 5, cg = tid & 31;
  int c0 = cg * 2;
  int row = tile0 + r;
  // per-thread redundant wmix (broadcast loads)
  float W0 = 0.0f, W1 = 0.0f;
#pragma unroll
  for (int h = 0; h < NH; ++h) {
    float s0 = scores[(size_t)(h * KH + 0) * NROW + row];
    float s1 = scores[(size_t)(h * KH + 1) * NROW + row];
    float m = fmaxf(s0, s1);
    float e0 = __expf(s0 - m), e1 = __expf(s1 - m);
    float inv = 1.0f / (e0 + e1);
    W0 += e0 * inv; W1 += e1 * inv;
  }
  W0 *= 0.25f; W1 *= 0.25f;
  float2 enc2 = *(const float2*)(encIn + (size_t)row * DD + c0);
  float2 g0 = *(const float2*)(agg + (size_t)row * DD + c0);
  float2 g1 = *(const float2*)(agg + (size_t)(NROW + row) * DD + c0);
  X[r][c0]     = W0 * g0.x + W1 * g1.x;
  X[r][c0 + 1] = W0 * g0.y + W1 * g1.y;
  X[r][64 + c0]     = enc2.x;
  X[r][64 + c0 + 1] = enc2.y;
  __syncthreads();
  // u, r gates over xs=[nxt|enc]
  float au0 = bu[c0], au1 = bu[c0 + 1];
  float ar0 = br[c0], ar1 = br[c0 + 1];
#pragma unroll 16
  for (int kk = 0; kk < 2 * DD; ++kk) {
    float x = X[r][kk];
    float2 u2 = *(const float2*)(wu + kk * DD + c0);
    float2 r2 = *(const float2*)(wr + kk * DD + c0);
    au0 = fmaf(x, u2.x, au0); au1 = fmaf(x, u2.y, au1);
    ar0 = fmaf(x, r2.x, ar0); ar1 = fmaf(x, r2.y, ar1);
  }
  float uu0 = sigmoid_f(au0), uu1 = sigmoid_f(au1);
  float rr0 = sigmoid_f(ar0), rr1 = sigmoid_f(ar1);
  __syncthreads();                 // all reads of X done before overwrite
  X[r][64 + c0]     = enc2.x * rr0;
  X[r][64 + c0 + 1] = enc2.y * rr1;
  __syncthreads();
  // candidate
  float ac0 = bc[c0], ac1 = bc[c0 + 1];
#pragma unroll 16
  for (int kk = 0; kk < 2 * DD; ++kk) {
    float x = X[r][kk];
    float2 c2 = *(const float2*)(wc + kk * DD + c0);
    ac0 = fmaf(x, c2.x, ac0); ac1 = fmaf(x, c2.y, ac1);
  }
  float eo0 = uu0 * enc2.x + (1.0f - uu0) * tanh_f(ac0);
  float eo1 = uu1 * enc2.y + (1.0f - uu1) * tanh_f(ac1);
  float2 eo2; eo2.x = eo0; eo2.y = eo1;
  *(float2*)(encOut + (size_t)row * DD + c0) = eo2;
  if (do_decode) {
    __syncthreads();               // candidate reads done; reuse X[.][0..63]
    X[r][c0] = eo0; X[r][c0 + 1] = eo1;
    __syncthreads();
    float hd0 = db0[c0], hd1 = db0[c0 + 1];
    float hq0 = ub0[c0], hq1 = ub0[c0 + 1];
#pragma unroll 16
    for (int kk = 0; kk < DD; ++kk) {
      float x = X[r][kk];
      float2 d2 = *(const float2*)(dw0 + kk * DD + c0);
      float2 q2 = *(const float2*)(uw0 + kk * DD + c0);
      hd0 = fmaf(x, d2.x, hd0); hd1 = fmaf(x, d2.y, hd1);
      hq0 = fmaf(x, q2.x, hq0); hq1 = fmaf(x, q2.y, hq1);
    }
    float2 dv = *(const float2*)(dw1 + c0);
    float2 qv = *(const float2*)(uw1 + c0);
    float p = hd0 * dv.x + hd1 * dv.y;
    float q = hq0 * qv.x + hq1 * qv.y;
    p = hredsum(p);
    q = hredsum(q);
    if (cg == 0) {
      pred[row] = p + db1[0];
      dualp[row] = q + ub1[0];
    }
  }
}

// ------- fused: sparsemax (fixed-point tau) + CSC scatter + dual edge cost -------
__global__ void __launch_bounds__(256) k_primal_dual(
    const int* __restrict__ nb_cols, const int* __restrict__ nb_cnt,
    const float* __restrict__ pred, const float* __restrict__ dualp,
    const float* __restrict__ dem,
    float* __restrict__ rowsum,
    int* __restrict__ col_cnt, int* __restrict__ col_rows, float* __restrict__ col_vals,
    float* __restrict__ out) {
  __shared__ float bacc[BB];
  if (threadIdx.x < BB) bacc[threadIdx.x] = 0.0f;
  __syncthreads();
  int w = threadIdx.x >> 6, lane = threadIdx.x & 63;
  int row = blockIdx.x * 4 + w;
  int b = row / VV;
  int n = nb_cnt[row];
  int c = (lane < n) ? nb_cols[(size_t)row * CAP + lane] : 0;
  const float* predB = pred + (size_t)b * VV;
  const float* dualB = dualp + (size_t)b * VV;
  float z = (lane < n) ? predB[c] : -1e30f;
  float tau = 0.0f;
  if (n > 0) {
    bool in = (lane < n);
    for (int it = 0; it < 64; ++it) {
      float s = wredsum(in ? z : 0.0f);
      int cnt = (int)__popcll(__ballot(in));
      tau = (s - 1.0f) / (float)cnt;
      bool nin = (z > tau);
      if (__ballot(nin) == __ballot(in)) break;
      in = nin;
    }
  }
  float pv = (lane < n) ? fmaxf(z - tau, 0.0f) : 0.0f;
  float s2 = wredsum(pv * pv);
  if (lane == 0) rowsum[row] = s2;
  if (pv > 0.0f) {
    int g = b * VV + c;
    int j = atomicAdd(&col_cnt[g], 1);
    if (j < CAP) {
      col_rows[(size_t)g * CAP + j] = row - b * VV;
      col_vals[(size_t)g * CAP + j] = pv;
    }
  }
  float du = dualp[row];
  float es = 0.0f;
  if (lane < n) {
    float dd = du - dualB[c];
    float f = 0.0f, acm = 0.0f;
#pragma unroll
    for (int t = 0; t < 8; ++t) {
      float look = f - 0.9f * acm;
      float grad = 2.0f * look - dd;
      acm = 0.9f * acm + 0.1f * grad;
      f = fmaxf(f - acm, 0.0f);
    }
    es = f * f - dd * f;
  }
  float contrib = -es;
  if (lane == 0) contrib += du * dem[row];
  float ws_ = wredsum(contrib);
  if (lane == 0) atomicAdd(&bacc[b], ws_);
  __syncthreads();
  if (threadIdx.x < BB) {
    float t = bacc[threadIdx.x];
    if (t != 0.0f) atomicAdd(&out[threadIdx.x], t);
  }
}

// ------- fused flow iterations (per-graph block) + flow cost -------
__global__ void __launch_bounds__(1024) k_flow(
    const int* __restrict__ col_cnt, const int* __restrict__ col_rows,
    const float* __restrict__ col_vals, const float* __restrict__ dem,
    const float* __restrict__ rowsum, float* __restrict__ out) {
  __shared__ float aS[VV];
  __shared__ float red[16];
  int b = blockIdx.x;
  int tid = threadIdx.x;
  const float* demB = dem + (size_t)b * VV;
  for (int v = tid; v < VV; v += 1024) aS[v] = fmaxf(-demB[v], 0.0f);
  __syncthreads();
  for (int t = 0; t < 7; ++t) {
    float nv0 = 0.0f, nv1 = 0.0f;
    {
      int v = tid;
      if (v < VV) {
        int g = b * VV + v;
        int n = col_cnt[g]; if (n > CAP) n = CAP;
        const int* cr = col_rows + (size_t)g * CAP;
        const float* cv = col_vals + (size_t)g * CAP;
        float acc = 0.0f;
        for (int j = 0; j < n; ++j) acc += cv[j] * aS[cr[j]];
        nv0 = fmaxf(acc - demB[v], 0.0f);
      }
      v = tid + 1024;
      if (v < VV) {
        int g = b * VV + v;
        int n = col_cnt[g]; if (n > CAP) n = CAP;
        const int* cr = col_rows + (size_t)g * CAP;
        const float* cv = col_vals + (size_t)g * CAP;
        float acc = 0.0f;
        for (int j = 0; j < n; ++j) acc += cv[j] * aS[cr[j]];
        nv1 = fmaxf(acc - demB[v], 0.0f);
      }
    }
    __syncthreads();
    if (tid < VV) aS[tid] = nv0;
    if (tid + 1024 < VV) aS[tid + 1024] = nv1;
    __syncthreads();
  }
  float fc = 0.0f;
  for (int v = tid; v < VV; v += 1024) { float a = aS[v]; fc += a * a * rowsum[b * VV + v]; }
  fc = wredsum(fc);
  int wid = tid >> 6, lane = tid & 63;
  if (lane == 0) red[wid] = fc;
  __syncthreads();
  if (tid == 0) {
    float s = 0.0f;
#pragma unroll
    for (int i = 0; i < 16; ++i) s += red[i];
    atomicAdd(&out[b], s);
  }
}

extern "C" void kernel_launch(void* const* d_in, const int* in_sizes, int n_in,
                              void* d_out, int out_size, void* d_ws, size_t ws_size,
                              hipStream_t stream) {
  const float* feat   = (const float*)d_in[0];
  const float* emb    = (const float*)d_in[1];
  const float* dem    = (const float*)d_in[2];
  const float* nb     = (const float*)d_in[4];   // [K,B,V,V]
  const float* enc_w0 = (const float*)d_in[5];
  const float* enc_b0 = (const float*)d_in[6];
  const float* enc_w1 = (const float*)d_in[7];
  const float* enc_b1 = (const float*)d_in[8];
  const float* agg_w  = (const float*)d_in[9];
  const float* agg_b  = (const float*)d_in[10];
  const float* att_w  = (const float*)d_in[11];
  const float* att_b  = (const float*)d_in[12];
  const float* att_v  = (const float*)d_in[13];
  const float* gru_wu = (const float*)d_in[14];
  const float* gru_bu = (const float*)d_in[15];
  const float* gru_wr = (const float*)d_in[16];
  const float* gru_br = (const float*)d_in[17];
  const float* gru_wc = (const float*)d_in[18];
  const float* gru_bc = (const float*)d_in[19];
  const float* dec_w0 = (const float*)d_in[20];
  const float* dec_b0 = (const float*)d_in[21];
  const float* dec_w1 = (const float*)d_in[22];
  const float* dec_b1 = (const float*)d_in[23];
  const float* dual_w0= (const float*)d_in[24];
  const float* dual_b0= (const float*)d_in[25];
  const float* dual_w1= (const float*)d_in[26];
  const float* dual_b1= (const float*)d_in[27];
  float* out = (float*)d_out;

  float* ws = (float*)d_ws;
  float* enc0     = ws;                              // NROW*DD
  float* enc1     = enc0 + (size_t)NROW * DD;
  float* msg      = enc1 + (size_t)NROW * DD;        // NKROW*DD
  float* aggbuf   = msg + (size_t)NKROW * DD;        // NKROW*DD
  float* scores   = aggbuf + (size_t)NKROW * DD;     // NH*KH*NROW
  float* pred     = scores + (size_t)NH * KH * NROW;
  float* dualp    = pred + NROW;
  float* rowsum   = dualp + NROW;
  float* col_vals = rowsum + NROW;                   // NROW*CAP
  int* col_cnt  = (int*)(col_vals + (size_t)NROW * CAP);
  int* nb_cnt   = col_cnt + NROW;                    // NKROW
  int* col_rows = nb_cnt + NKROW;                    // NROW*CAP
  int* nb_cols  = col_rows + (size_t)NROW * CAP;

  (void)in_sizes; (void)n_in; (void)ws_size;

  hipMemsetAsync(out, 0, (size_t)out_size * sizeof(float), stream);
  hipMemsetAsync(col_cnt, 0, (size_t)NROW * sizeof(int), stream);

  k_nbcsr<<<NKROW / 4, 256, 0, stream>>>(nb, nb_cols, nb_cnt);
  k_encoder<<<NROW / 8, 256, 0, stream>>>(emb, feat, enc_w0, enc_b0, enc_w1, enc_b1, enc0);

  const float* encIn = enc0;
  float* encOut = enc1;
  for (int l = 0; l < 2; ++l) {
    k_gather<<<NKROW / 4, 256, 0, stream>>>(nb_cols, nb_cnt, encIn, msg);
    k_aggatt<<<NKROW / 8, 256, 0, stream>>>(msg, agg_w, agg_b, att_w, att_b, att_v,
                                            aggbuf, scores);
    k_gru<<<NROW / 8, 256, 0, stream>>>(encIn, aggbuf, scores,
                                        gru_wu, gru_bu, gru_wr, gru_br, gru_wc, gru_bc,
                                        encOut,
                                        (l == 1) ? 1 : 0,
                                        dec_w0, dec_b0, dec_w1, dec_b1,
                                        dual_w0, dual_b0, dual_w1, dual_b1, pred, dualp);
    const float* t = encIn; encIn = encOut; encOut = (float*)t;
  }

  k_primal_dual<<<NROW / 4, 256, 0, stream>>>(nb_cols, nb_cnt, pred, dualp, dem,
                                              rowsum, col_cnt, col_rows, col_vals, out);
  k_flow<<<BB, 1024, 0, stream>>>(col_cnt, col_rows, col_vals, dem, rowsum, out);
}

// Round 8
// 561.828 us; speedup vs baseline: 1.2997x; 1.2997x over previous
//
#include <hip/hip_runtime.h>

#define BB 8
#define VV 1200
#define DD 64
#define KH 2     // hops
#define NH 4     // heads
#define CAP 64        // hop1 cap
#define NB2CAP 384    // hop2 cap
#define NROW (BB*VV)          // 9600
#define NKROW (KH*BB*VV)      // 19200

__device__ __forceinline__ float wredsum(float v) {
#pragma unroll
  for (int o = 32; o > 0; o >>= 1) v += __shfl_xor(v, o, 64);
  return v;
}
// reduce across the 16 lanes of a cg-group (lanes sharing rsub)
__device__ __forceinline__ float gredsum(float v) {
#pragma unroll
  for (int o = 8; o > 0; o >>= 1) v += __shfl_xor(v, o, 64);
  return v;
}

// fast tanh via hw exp: tanh(x) = 1 - 2/(e^{2x}+1)
__device__ __forceinline__ float tanh_f(float x) {
  float e = __expf(2.0f * x);
  return 1.0f - 2.0f / (e + 1.0f);
}
__device__ __forceinline__ float sigmoid_f(float x) { return 1.0f / (1.0f + __expf(-x)); }

__device__ __forceinline__ size_t nb_base(int row) {
  return (row < NROW) ? (size_t)row * CAP
                      : (size_t)NROW * CAP + (size_t)(row - NROW) * NB2CAP;
}

// ---------------- build CSR of binary neighborhoods (dense 92MB read once) ----------------
__global__ void __launch_bounds__(256) k_nbcsr(
    const float* __restrict__ nb,
    int* __restrict__ nb_cols, int* __restrict__ nb_cnt) {
  int wid = threadIdx.x >> 6, lane = threadIdx.x & 63;
  int row = blockIdx.x * 4 + wid;
  if (row >= NKROW) return;
  const float* nbrow = nb + (size_t)row * VV;
  size_t base = nb_base(row);
  int cap = (row < NROW) ? CAP : NB2CAP;
  unsigned long long ltmask = (lane == 0) ? 0ull : ((1ull << lane) - 1ull);
  int cnt = 0;
  for (int b0 = 0; b0 < VV; b0 += 64) {
    int v = b0 + lane;
    float val = (v < VV) ? nbrow[v] : 0.0f;
    unsigned long long mask = __ballot(val != 0.0f);
    int off = cnt + __popcll(mask & ltmask);
    if (val != 0.0f && off < cap) nb_cols[base + off] = v;
    cnt += __popcll(mask);
  }
  if (lane == 0) nb_cnt[row] = (cnt > cap) ? cap : cnt;
}

// ---------------- encoder: 8 rows/block, thread=(row, col-pair) ----------------
__global__ void __launch_bounds__(256) k_encoder(
    const float* __restrict__ emb, const float* __restrict__ feat,
    const float* __restrict__ w0, const float* __restrict__ b0,
    const float* __restrict__ w1, const float* __restrict__ b1,
    float* __restrict__ enc0) {
  __shared__ float xT[8][25];
  __shared__ float hT[8][65];
  int tid = threadIdx.x;
  int tile0 = blockIdx.x * 8;
  if (tid < 128) { int i = tid >> 4, d = tid & 15; xT[i][d] = emb[(size_t)(tile0 + i) * 16 + d]; }
  else if (tid < 192) { int t = tid - 128; int i = t >> 3, d = t & 7; xT[i][16 + d] = feat[(size_t)(tile0 + i) * 8 + d]; }
  __syncthreads();
  int r = tid >> 5, cg = tid & 31;
  int c0 = cg * 2;
  float a0 = b0[c0], a1 = b0[c0 + 1];
#pragma unroll
  for (int kk = 0; kk < 24; ++kk) {
    float x = xT[r][kk];
    float2 w2 = *(const float2*)(w0 + kk * DD + c0);
    a0 = fmaf(x, w2.x, a0); a1 = fmaf(x, w2.y, a1);
  }
  hT[r][c0] = tanh_f(a0); hT[r][c0 + 1] = tanh_f(a1);
  __syncthreads();
  float g0 = b1[c0], g1 = b1[c0 + 1];
#pragma unroll 16
  for (int kk = 0; kk < DD; ++kk) {
    float x = hT[r][kk];
    float2 w2 = *(const float2*)(w1 + kk * DD + c0);
    g0 = fmaf(x, w2.x, g0); g1 = fmaf(x, w2.y, g1);
  }
  float2 o; o.x = tanh_f(g0); o.y = tanh_f(g1);
  *(float2*)(enc0 + (size_t)(tile0 + r) * DD + c0) = o;
}

// ---------------- gather: wave per row, float4 lanes, deep ILP ----------------
__global__ void __launch_bounds__(256) k_gather(
    const int* __restrict__ nb_cols, const int* __restrict__ nb_cnt,
    const float* __restrict__ encIn, float* __restrict__ msg) {
  int w = threadIdx.x >> 6, lane = threadIdx.x & 63;
  int row = blockIdx.x * 4 + w;           // [0, NKROW)
  int k = (row >= NROW) ? 1 : 0;
  int bv = row - k * NROW;
  int b = bv / VV;
  const float4* enc4 = (const float4*)(encIn + (size_t)b * VV * DD);
  const int* cols = nb_cols + nb_base(row);
  int n = nb_cnt[row];
  int sub = lane >> 4, q = lane & 15;
  float ax = 0.0f, ay = 0.0f, az = 0.0f, aw = 0.0f;
  int j = 0;
  for (; j + 16 <= n; j += 16) {
    int c0 = cols[j + sub];
    int c1 = cols[j + 4 + sub];
    int c2 = cols[j + 8 + sub];
    int c3 = cols[j + 12 + sub];
    float4 v0 = enc4[(size_t)c0 * 16 + q];
    float4 v1 = enc4[(size_t)c1 * 16 + q];
    float4 v2 = enc4[(size_t)c2 * 16 + q];
    float4 v3 = enc4[(size_t)c3 * 16 + q];
    ax += (v0.x + v1.x) + (v2.x + v3.x);
    ay += (v0.y + v1.y) + (v2.y + v3.y);
    az += (v0.z + v1.z) + (v2.z + v3.z);
    aw += (v0.w + v1.w) + (v2.w + v3.w);
  }
  for (; j < n; j += 4) {
    int idx = j + sub;
    if (idx < n) {
      float4 v = enc4[(size_t)cols[idx] * 16 + q];
      ax += v.x; ay += v.y; az += v.z; aw += v.w;
    }
  }
#pragma unroll
  for (int o = 16; o < 64; o <<= 1) {
    ax += __shfl_xor(ax, o, 64);
    ay += __shfl_xor(ay, o, 64);
    az += __shfl_xor(az, o, 64);
    aw += __shfl_xor(aw, o, 64);
  }
  if (lane < 16) {
    float inv = 1.0f / fmaxf((float)n, 1.0f);
    float4 r; r.x = ax * inv; r.y = ay * inv; r.z = az * inv; r.w = aw * inv;
    ((float4*)(msg + (size_t)row * DD))[q] = r;
  }
}

// ---------------- agg GEMM + attention scores: 64-row tile, 4x4 register tile ----------------
__global__ void __launch_bounds__(256) k_aggatt(
    const float* __restrict__ msg,
    const float* __restrict__ agg_w, const float* __restrict__ agg_b,
    const float* __restrict__ att_w, const float* __restrict__ att_b,
    const float* __restrict__ att_v,
    float* __restrict__ agg, float* __restrict__ scores) {
  __shared__ float M[64][65];
  __shared__ float G[64][65];
  int tid = threadIdx.x;
  int tile0 = blockIdx.x * 64;            // [0, NKROW)
  int k = (tile0 >= NROW) ? 1 : 0;
  int bv0 = tile0 - k * NROW;
  int rsub = tid >> 4, cg = tid & 15;
  int c0 = cg * 4;
  int r0 = rsub * 4;
  // load 64x64 msg tile
#pragma unroll
  for (int rep = 0; rep < 4; ++rep) {
    int idx = rep * 256 + tid; int i = idx >> 4, d4 = idx & 15;
    float4 m4 = *(const float4*)(msg + (size_t)(tile0 + i) * DD + d4 * 4);
    M[i][d4 * 4] = m4.x; M[i][d4 * 4 + 1] = m4.y; M[i][d4 * 4 + 2] = m4.z; M[i][d4 * 4 + 3] = m4.w;
  }
  __syncthreads();
  // agg GEMM: 4x4 tile per thread
  const float* W = agg_w + (size_t)k * DD * DD;
  float acc[4][4];
#pragma unroll
  for (int i = 0; i < 4; ++i)
#pragma unroll
    for (int j = 0; j < 4; ++j) acc[i][j] = agg_b[k * DD + c0 + j];
#pragma unroll 4
  for (int kk = 0; kk < DD; ++kk) {
    float4 w4 = *(const float4*)(W + kk * DD + c0);
    float x0 = M[r0][kk], x1 = M[r0 + 1][kk], x2 = M[r0 + 2][kk], x3 = M[r0 + 3][kk];
    acc[0][0] = fmaf(x0, w4.x, acc[0][0]); acc[0][1] = fmaf(x0, w4.y, acc[0][1]);
    acc[0][2] = fmaf(x0, w4.z, acc[0][2]); acc[0][3] = fmaf(x0, w4.w, acc[0][3]);
    acc[1][0] = fmaf(x1, w4.x, acc[1][0]); acc[1][1] = fmaf(x1, w4.y, acc[1][1]);
    acc[1][2] = fmaf(x1, w4.z, acc[1][2]); acc[1][3] = fmaf(x1, w4.w, acc[1][3]);
    acc[2][0] = fmaf(x2, w4.x, acc[2][0]); acc[2][1] = fmaf(x2, w4.y, acc[2][1]);
    acc[2][2] = fmaf(x2, w4.z, acc[2][2]); acc[2][3] = fmaf(x2, w4.w, acc[2][3]);
    acc[3][0] = fmaf(x3, w4.x, acc[3][0]); acc[3][1] = fmaf(x3, w4.y, acc[3][1]);
    acc[3][2] = fmaf(x3, w4.z, acc[3][2]); acc[3][3] = fmaf(x3, w4.w, acc[3][3]);
  }
#pragma unroll
  for (int i = 0; i < 4; ++i) {
    float4 g4;
    g4.x = tanh_f(acc[i][0]); g4.y = tanh_f(acc[i][1]);
    g4.z = tanh_f(acc[i][2]); g4.w = tanh_f(acc[i][3]);
    G[r0 + i][c0] = g4.x; G[r0 + i][c0 + 1] = g4.y; G[r0 + i][c0 + 2] = g4.z; G[r0 + i][c0 + 3] = g4.w;
    *(float4*)(agg + (size_t)(tile0 + r0 + i) * DD + c0) = g4;
  }
  __syncthreads();
  // attention heads
#pragma unroll
  for (int h = 0; h < NH; ++h) {
    const float* Wh = att_w + (size_t)h * DD * DD;
    float a2[4][4];
#pragma unroll
    for (int i = 0; i < 4; ++i)
#pragma unroll
      for (int j = 0; j < 4; ++j) a2[i][j] = att_b[h * DD + c0 + j];
#pragma unroll 4
    for (int kk = 0; kk < DD; ++kk) {
      float4 w4 = *(const float4*)(Wh + kk * DD + c0);
      float x0 = G[r0][kk], x1 = G[r0 + 1][kk], x2 = G[r0 + 2][kk], x3 = G[r0 + 3][kk];
      a2[0][0] = fmaf(x0, w4.x, a2[0][0]); a2[0][1] = fmaf(x0, w4.y, a2[0][1]);
      a2[0][2] = fmaf(x0, w4.z, a2[0][2]); a2[0][3] = fmaf(x0, w4.w, a2[0][3]);
      a2[1][0] = fmaf(x1, w4.x, a2[1][0]); a2[1][1] = fmaf(x1, w4.y, a2[1][1]);
      a2[1][2] = fmaf(x1, w4.z, a2[1][2]); a2[1][3] = fmaf(x1, w4.w, a2[1][3]);
      a2[2][0] = fmaf(x2, w4.x, a2[2][0]); a2[2][1] = fmaf(x2, w4.y, a2[2][1]);
      a2[2][2] = fmaf(x2, w4.z, a2[2][2]); a2[2][3] = fmaf(x2, w4.w, a2[2][3]);
      a2[3][0] = fmaf(x3, w4.x, a2[3][0]); a2[3][1] = fmaf(x3, w4.y, a2[3][1]);
      a2[3][2] = fmaf(x3, w4.z, a2[3][2]); a2[3][3] = fmaf(x3, w4.w, a2[3][3]);
    }
    float4 v4 = *(const float4*)(att_v + h * DD + c0);
#pragma unroll
    for (int i = 0; i < 4; ++i) {
      float p = tanh_f(a2[i][0]) * v4.x + tanh_f(a2[i][1]) * v4.y
              + tanh_f(a2[i][2]) * v4.z + tanh_f(a2[i][3]) * v4.w;
      p = gredsum(p);   // reduce over 16 cg lanes
      if (cg == 0) scores[(size_t)(h * KH + k) * NROW + bv0 + r0 + i] = p;
    }
  }
}

// ---------------- attention mix + GRU (+ fused decode): 64-row tile, 4x4 reg tile ----------------
__global__ void __launch_bounds__(256) k_gru(
    const float* __restrict__ encIn, const float* __restrict__ agg,
    const float* __restrict__ scores,
    const float* __restrict__ wu, const float* __restrict__ bu,
    const float* __restrict__ wr, const float* __restrict__ br,
    const float* __restrict__ wc, const float* __restrict__ bc,
    float* __restrict__ encOut,
    int do_decode,
    const float* __restrict__ dw0, const float* __restrict__ db0,
    const float* __restrict__ dw1, const float* __restrict__ db1,
    const float* __restrict__ uw0, const float* __restrict__ ub0,
    const float* __restrict__ uw1, const float* __restrict__ ub1,
    float* __restrict__ pred, float* __restrict__ dualp) {
  __shared__ float X[64][129];     // [row][0..63]=nxt, [64..127]=enc then r*enc
  __shared__ float EO[64][65];     // output tile (decode input)
  __shared__ float wmix[2][64];
  int tid = threadIdx.x;
  int tile0 = blockIdx.x * 64;
  int rsub = tid >> 4, cg = tid & 15;
  int c0 = cg * 4;
  int r0 = rsub * 4;
  // wmix per row
  if (tid < 64) {
    int row = tile0 + tid;
    float W0 = 0.0f, W1 = 0.0f;
#pragma unroll
    for (int h = 0; h < NH; ++h) {
      float s0 = scores[(size_t)(h * KH + 0) * NROW + row];
      float s1 = scores[(size_t)(h * KH + 1) * NROW + row];
      float m = fmaxf(s0, s1);
      float e0 = __expf(s0 - m), e1 = __expf(s1 - m);
      float inv = 1.0f / (e0 + e1);
      W0 += e0 * inv; W1 += e1 * inv;
    }
    wmix[0][tid] = W0 * 0.25f;
    wmix[1][tid] = W1 * 0.25f;
  }
  __syncthreads();
  // load enc + mixed agg tiles
#pragma unroll
  for (int rep = 0; rep < 4; ++rep) {
    int idx = rep * 256 + tid; int i = idx >> 4, d4 = idx & 15;
    float4 e4 = *(const float4*)(encIn + (size_t)(tile0 + i) * DD + d4 * 4);
    float4 a0 = *(const float4*)(agg + (size_t)(tile0 + i) * DD + d4 * 4);
    float4 a1 = *(const float4*)(agg + (size_t)(NROW + tile0 + i) * DD + d4 * 4);
    float m0 = wmix[0][i], m1 = wmix[1][i];
    X[i][d4 * 4]     = m0 * a0.x + m1 * a1.x;
    X[i][d4 * 4 + 1] = m0 * a0.y + m1 * a1.y;
    X[i][d4 * 4 + 2] = m0 * a0.z + m1 * a1.z;
    X[i][d4 * 4 + 3] = m0 * a0.w + m1 * a1.w;
    X[i][64 + d4 * 4]     = e4.x;
    X[i][64 + d4 * 4 + 1] = e4.y;
    X[i][64 + d4 * 4 + 2] = e4.z;
    X[i][64 + d4 * 4 + 3] = e4.w;
  }
  __syncthreads();
  // u, r gates over xs=[nxt|enc]
  float au[4][4], ar[4][4];
#pragma unroll
  for (int i = 0; i < 4; ++i)
#pragma unroll
    for (int j = 0; j < 4; ++j) { au[i][j] = bu[c0 + j]; ar[i][j] = br[c0 + j]; }
#pragma unroll 4
  for (int kk = 0; kk < 2 * DD; ++kk) {
    float4 u4 = *(const float4*)(wu + kk * DD + c0);
    float4 r4 = *(const float4*)(wr + kk * DD + c0);
    float x0 = X[r0][kk], x1 = X[r0 + 1][kk], x2 = X[r0 + 2][kk], x3 = X[r0 + 3][kk];
    au[0][0] = fmaf(x0, u4.x, au[0][0]); au[0][1] = fmaf(x0, u4.y, au[0][1]);
    au[0][2] = fmaf(x0, u4.z, au[0][2]); au[0][3] = fmaf(x0, u4.w, au[0][3]);
    au[1][0] = fmaf(x1, u4.x, au[1][0]); au[1][1] = fmaf(x1, u4.y, au[1][1]);
    au[1][2] = fmaf(x1, u4.z, au[1][2]); au[1][3] = fmaf(x1, u4.w, au[1][3]);
    au[2][0] = fmaf(x2, u4.x, au[2][0]); au[2][1] = fmaf(x2, u4.y, au[2][1]);
    au[2][2] = fmaf(x2, u4.z, au[2][2]); au[2][3] = fmaf(x2, u4.w, au[2][3]);
    au[3][0] = fmaf(x3, u4.x, au[3][0]); au[3][1] = fmaf(x3, u4.y, au[3][1]);
    au[3][2] = fmaf(x3, u4.z, au[3][2]); au[3][3] = fmaf(x3, u4.w, au[3][3]);
    ar[0][0] = fmaf(x0, r4.x, ar[0][0]); ar[0][1] = fmaf(x0, r4.y, ar[0][1]);
    ar[0][2] = fmaf(x0, r4.z, ar[0][2]); ar[0][3] = fmaf(x0, r4.w, ar[0][3]);
    ar[1][0] = fmaf(x1, r4.x, ar[1][0]); ar[1][1] = fmaf(x1, r4.y, ar[1][1]);
    ar[1][2] = fmaf(x1, r4.z, ar[1][2]); ar[1][3] = fmaf(x1, r4.w, ar[1][3]);
    ar[2][0] = fmaf(x2, r4.x, ar[2][0]); ar[2][1] = fmaf(x2, r4.y, ar[2][1]);
    ar[2][2] = fmaf(x2, r4.z, ar[2][2]); ar[2][3] = fmaf(x2, r4.w, ar[2][3]);
    ar[3][0] = fmaf(x3, r4.x, ar[3][0]); ar[3][1] = fmaf(x3, r4.y, ar[3][1]);
    ar[3][2] = fmaf(x3, r4.z, ar[3][2]); ar[3][3] = fmaf(x3, r4.w, ar[3][3]);
  }
  float uu[4][4], encv[4][4];
#pragma unroll
  for (int i = 0; i < 4; ++i)
#pragma unroll
    for (int j = 0; j < 4; ++j) {
      uu[i][j] = sigmoid_f(au[i][j]);
      encv[i][j] = X[r0 + i][64 + c0 + j];
    }
  __syncthreads();    // all gate-pass reads of X done
#pragma unroll
  for (int i = 0; i < 4; ++i)
#pragma unroll
    for (int j = 0; j < 4; ++j)
      X[r0 + i][64 + c0 + j] = encv[i][j] * sigmoid_f(ar[i][j]);
  __syncthreads();
  // candidate
  float ac[4][4];
#pragma unroll
  for (int i = 0; i < 4; ++i)
#pragma unroll
    for (int j = 0; j < 4; ++j) ac[i][j] = bc[c0 + j];
#pragma unroll 4
  for (int kk = 0; kk < 2 * DD; ++kk) {
    float4 c4 = *(const float4*)(wc + kk * DD + c0);
    float x0 = X[r0][kk], x1 = X[r0 + 1][kk], x2 = X[r0 + 2][kk], x3 = X[r0 + 3][kk];
    ac[0][0] = fmaf(x0, c4.x, ac[0][0]); ac[0][1] = fmaf(x0, c4.y, ac[0][1]);
    ac[0][2] = fmaf(x0, c4.z, ac[0][2]); ac[0][3] = fmaf(x0, c4.w, ac[0][3]);
    ac[1][0] = fmaf(x1, c4.x, ac[1][0]); ac[1][1] = fmaf(x1, c4.y, ac[1][1]);
    ac[1][2] = fmaf(x1, c4.z, ac[1][2]); ac[1][3] = fmaf(x1, c4.w, ac[1][3]);
    ac[2][0] = fmaf(x2, c4.x, ac[2][0]); ac[2][1] = fmaf(x2, c4.y, ac[2][1]);
    ac[2][2] = fmaf(x2, c4.z, ac[2][2]); ac[2][3] = fmaf(x2, c4.w, ac[2][3]);
    ac[3][0] = fmaf(x3, c4.x, ac[3][0]); ac[3][1] = fmaf(x3, c4.y, ac[3][1]);
    ac[3][2] = fmaf(x3, c4.z, ac[3][2]); ac[3][3] = fmaf(x3, c4.w, ac[3][3]);
  }
#pragma unroll
  for (int i = 0; i < 4; ++i) {
    float4 e4;
    e4.x = uu[i][0] * encv[i][0] + (1.0f - uu[i][0]) * tanh_f(ac[i][0]);
    e4.y = uu[i][1] * encv[i][1] + (1.0f - uu[i][1]) * tanh_f(ac[i][1]);
    e4.z = uu[i][2] * encv[i][2] + (1.0f - uu[i][2]) * tanh_f(ac[i][2]);
    e4.w = uu[i][3] * encv[i][3] + (1.0f - uu[i][3]) * tanh_f(ac[i][3]);
    *(float4*)(encOut + (size_t)(tile0 + r0 + i) * DD + c0) = e4;
    EO[r0 + i][c0] = e4.x; EO[r0 + i][c0 + 1] = e4.y;
    EO[r0 + i][c0 + 2] = e4.z; EO[r0 + i][c0 + 3] = e4.w;
  }
  if (do_decode) {
    __syncthreads();
    float hd[4][4], hq[4][4];
#pragma unroll
    for (int i = 0; i < 4; ++i)
#pragma unroll
      for (int j = 0; j < 4; ++j) { hd[i][j] = db0[c0 + j]; hq[i][j] = ub0[c0 + j]; }
#pragma unroll 4
    for (int kk = 0; kk < DD; ++kk) {
      float4 d4 = *(const float4*)(dw0 + kk * DD + c0);
      float4 q4 = *(const float4*)(uw0 + kk * DD + c0);
      float x0 = EO[r0][kk], x1 = EO[r0 + 1][kk], x2 = EO[r0 + 2][kk], x3 = EO[r0 + 3][kk];
      hd[0][0] = fmaf(x0, d4.x, hd[0][0]); hd[0][1] = fmaf(x0, d4.y, hd[0][1]);
      hd[0][2] = fmaf(x0, d4.z, hd[0][2]); hd[0][3] = fmaf(x0, d4.w, hd[0][3]);
      hd[1][0] = fmaf(x1, d4.x, hd[1][0]); hd[1][1] = fmaf(x1, d4.y, hd[1][1]);
      hd[1][2] = fmaf(x1, d4.z, hd[1][2]); hd[1][3] = fmaf(x1, d4.w, hd[1][3]);
      hd[2][0] = fmaf(x2, d4.x, hd[2][0]); hd[2][1] = fmaf(x2, d4.y, hd[2][1]);
      hd[2][2] = fmaf(x2, d4.z, hd[2][2]); hd[2][3] = fmaf(x2, d4.w, hd[2][3]);
      hd[3][0] = fmaf(x3, d4.x, hd[3][0]); hd[3][1] = fmaf(x3, d4.y, hd[3][1]);
      hd[3][2] = fmaf(x3, d4.z, hd[3][2]); hd[3][3] = fmaf(x3, d4.w, hd[3][3]);
      hq[0][0] = fmaf(x0, q4.x, hq[0][0]); hq[0][1] = fmaf(x0, q4.y, hq[0][1]);
      hq[0][2] = fmaf(x0, q4.z, hq[0][2]); hq[0][3] = fmaf(x0, q4.w, hq[0][3]);
      hq[1][0] = fmaf(x1, q4.x, hq[1][0]); hq[1][1] = fmaf(x1, q4.y, hq[1][1]);
      hq[1][2] = fmaf(x1, q4.z, hq[1][2]); hq[1][3] = fmaf(x1, q4.w, hq[1][3]);
      hq[2][0] = fmaf(x2, q4.x, hq[2][0]); hq[2][1] = fmaf(x2, q4.y, hq[2][1]);
      hq[2][2] = fmaf(x2, q4.z, hq[2][2]); hq[2][3] = fmaf(x2, q4.w, hq[2][3]);
      hq[3][0] = fmaf(x3, q4.x, hq[3][0]); hq[3][1] = fmaf(x3, q4.y, hq[3][1]);
      hq[3][2] = fmaf(x3, q4.z, hq[3][2]); hq[3][3] = fmaf(x3, q4.w, hq[3][3]);
    }
    float4 dv = *(const float4*)(dw1 + c0);
    float4 qv = *(const float4*)(uw1 + c0);
#pragma unroll
    for (int i = 0; i < 4; ++i) {
      float p = hd[i][0] * dv.x + hd[i][1] * dv.y + hd[i][2] * dv.z + hd[i][3] * dv.w;
      float q = hq[i][0] * qv.x + hq[i][1] * qv.y + hq[i][2] * qv.z + hq[i][3] * qv.w;
      p = gredsum(p);
      q = gredsum(q);
      if (cg == 0) {
        pred[tile0 + r0 + i] = p + db1[0];
        dualp[tile0 + r0 + i] = q + ub1[0];
      }
    }
  }
}

// ------- fused: sparsemax (fixed-point tau) + CSC scatter + dual edge cost -------
__global__ void __launch_bounds__(256) k_primal_dual(
    const int* __restrict__ nb_cols, const int* __restrict__ nb_cnt,
    const float* __restrict__ pred, const float* __restrict__ dualp,
    const float* __restrict__ dem,
    float* __restrict__ rowsum,
    int* __restrict__ col_cnt, int* __restrict__ col_rows, float* __restrict__ col_vals,
    float* __restrict__ out) {
  __shared__ float bacc[BB];
  if (threadIdx.x < BB) bacc[threadIdx.x] = 0.0f;
  __syncthreads();
  int w = threadIdx.x >> 6, lane = threadIdx.x & 63;
  int row = blockIdx.x * 4 + w;
  int b = row / VV;
  int n = nb_cnt[row];
  int c = (lane < n) ? nb_cols[(size_t)row * CAP + lane] : 0;
  const float* predB = pred + (size_t)b * VV;
  const float* dualB = dualp + (size_t)b * VV;
  float z = (lane < n) ? predB[c] : -1e30f;
  float tau = 0.0f;
  if (n > 0) {
    bool in = (lane < n);
    for (int it = 0; it < 64; ++it) {
      float s = wredsum(in ? z : 0.0f);
      int cnt = (int)__popcll(__ballot(in));
      tau = (s - 1.0f) / (float)cnt;
      bool nin = (z > tau);
      if (__ballot(nin) == __ballot(in)) break;
      in = nin;
    }
  }
  float pv = (lane < n) ? fmaxf(z - tau, 0.0f) : 0.0f;
  float s2 = wredsum(pv * pv);
  if (lane == 0) rowsum[row] = s2;
  if (pv > 0.0f) {
    int g = b * VV + c;
    int j = atomicAdd(&col_cnt[g], 1);
    if (j < CAP) {
      col_rows[(size_t)g * CAP + j] = row - b * VV;
      col_vals[(size_t)g * CAP + j] = pv;
    }
  }
  float du = dualp[row];
  float es = 0.0f;
  if (lane < n) {
    float dd = du - dualB[c];
    float f = 0.0f, acm = 0.0f;
#pragma unroll
    for (int t = 0; t < 8; ++t) {
      float look = f - 0.9f * acm;
      float grad = 2.0f * look - dd;
      acm = 0.9f * acm + 0.1f * grad;
      f = fmaxf(f - acm, 0.0f);
    }
    es = f * f - dd * f;
  }
  float contrib = -es;
  if (lane == 0) contrib += du * dem[row];
  float ws_ = wredsum(contrib);
  if (lane == 0) atomicAdd(&bacc[b], ws_);
  __syncthreads();
  if (threadIdx.x < BB) {
    float t = bacc[threadIdx.x];
    if (t != 0.0f) atomicAdd(&out[threadIdx.x], t);
  }
}

// ------- fused flow iterations (per-graph block) + flow cost -------
__global__ void __launch_bounds__(1024) k_flow(
    const int* __restrict__ col_cnt, const int* __restrict__ col_rows,
    const float* __restrict__ col_vals, const float* __restrict__ dem,
    const float* __restrict__ rowsum, float* __restrict__ out) {
  __shared__ float aS[VV];
  __shared__ float red[16];
  int b = blockIdx.x;
  int tid = threadIdx.x;
  const float* demB = dem + (size_t)b * VV;
  for (int v = tid; v < VV; v += 1024) aS[v] = fmaxf(-demB[v], 0.0f);
  __syncthreads();
  for (int t = 0; t < 7; ++t) {
    float nv0 = 0.0f, nv1 = 0.0f;
    {
      int v = tid;
      if (v < VV) {
        int g = b * VV + v;
        int n = col_cnt[g]; if (n > CAP) n = CAP;
        const int* cr = col_rows + (size_t)g * CAP;
        const float* cv = col_vals + (size_t)g * CAP;
        float acc = 0.0f;
        for (int j = 0; j < n; ++j) acc += cv[j] * aS[cr[j]];
        nv0 = fmaxf(acc - demB[v], 0.0f);
      }
      v = tid + 1024;
      if (v < VV) {
        int g = b * VV + v;
        int n = col_cnt[g]; if (n > CAP) n = CAP;
        const int* cr = col_rows + (size_t)g * CAP;
        const float* cv = col_vals + (size_t)g * CAP;
        float acc = 0.0f;
        for (int j = 0; j < n; ++j) acc += cv[j] * aS[cr[j]];
        nv1 = fmaxf(acc - demB[v], 0.0f);
      }
    }
    __syncthreads();
    if (tid < VV) aS[tid] = nv0;
    if (tid + 1024 < VV) aS[tid + 1024] = nv1;
    __syncthreads();
  }
  float fc = 0.0f;
  for (int v = tid; v < VV; v += 1024) { float a = aS[v]; fc += a * a * rowsum[b * VV + v]; }
  fc = wredsum(fc);
  int wid = tid >> 6, lane = tid & 63;
  if (lane == 0) red[wid] = fc;
  __syncthreads();
  if (tid == 0) {
    float s = 0.0f;
#pragma unroll
    for (int i = 0; i < 16; ++i) s += red[i];
    atomicAdd(&out[b], s);
  }
}

extern "C" void kernel_launch(void* const* d_in, const int* in_sizes, int n_in,
                              void* d_out, int out_size, void* d_ws, size_t ws_size,
                              hipStream_t stream) {
  const float* feat   = (const float*)d_in[0];
  const float* emb    = (const float*)d_in[1];
  const float* dem    = (const float*)d_in[2];
  const float* nb     = (const float*)d_in[4];   // [K,B,V,V]
  const float* enc_w0 = (const float*)d_in[5];
  const float* enc_b0 = (const float*)d_in[6];
  const float* enc_w1 = (const float*)d_in[7];
  const float* enc_b1 = (const float*)d_in[8];
  const float* agg_w  = (const float*)d_in[9];
  const float* agg_b  = (const float*)d_in[10];
  const float* att_w  = (const float*)d_in[11];
  const float* att_b  = (const float*)d_in[12];
  const float* att_v  = (const float*)d_in[13];
  const float* gru_wu = (const float*)d_in[14];
  const float* gru_bu = (const float*)d_in[15];
  const float* gru_wr = (const float*)d_in[16];
  const float* gru_br = (const float*)d_in[17];
  const float* gru_wc = (const float*)d_in[18];
  const float* gru_bc = (const float*)d_in[19];
  const float* dec_w0 = (const float*)d_in[20];
  const float* dec_b0 = (const float*)d_in[21];
  const float* dec_w1 = (const float*)d_in[22];
  const float* dec_b1 = (const float*)d_in[23];
  const float* dual_w0= (const float*)d_in[24];
  const float* dual_b0= (const float*)d_in[25];
  const float* dual_w1= (const float*)d_in[26];
  const float* dual_b1= (const float*)d_in[27];
  float* out = (float*)d_out;

  float* ws = (float*)d_ws;
  float* enc0     = ws;                              // NROW*DD
  float* enc1     = enc0 + (size_t)NROW * DD;
  float* msg      = enc1 + (size_t)NROW * DD;        // NKROW*DD
  float* aggbuf   = msg + (size_t)NKROW * DD;        // NKROW*DD
  float* scores   = aggbuf + (size_t)NKROW * DD;     // NH*KH*NROW
  float* pred     = scores + (size_t)NH * KH * NROW;
  float* dualp    = pred + NROW;
  float* rowsum   = dualp + NROW;
  float* col_vals = rowsum + NROW;                   // NROW*CAP
  int* col_cnt  = (int*)(col_vals + (size_t)NROW * CAP);
  int* nb_cnt   = col_cnt + NROW;                    // NKROW
  int* col_rows = nb_cnt + NKROW;                    // NROW*CAP
  int* nb_cols  = col_rows + (size_t)NROW * CAP;

  (void)in_sizes; (void)n_in; (void)ws_size;

  hipMemsetAsync(out, 0, (size_t)out_size * sizeof(float), stream);
  hipMemsetAsync(col_cnt, 0, (size_t)NROW * sizeof(int), stream);

  k_nbcsr<<<NKROW / 4, 256, 0, stream>>>(nb, nb_cols, nb_cnt);
  k_encoder<<<NROW / 8, 256, 0, stream>>>(emb, feat, enc_w0, enc_b0, enc_w1, enc_b1, enc0);

  const float* encIn = enc0;
  float* encOut = enc1;
  for (int l = 0; l < 2; ++l) {
    k_gather<<<NKROW / 4, 256, 0, stream>>>(nb_cols, nb_cnt, encIn, msg);
    k_aggatt<<<NKROW / 64, 256, 0, stream>>>(msg, agg_w, agg_b, att_w, att_b, att_v,
                                             aggbuf, scores);
    k_gru<<<NROW / 64, 256, 0, stream>>>(encIn, aggbuf, scores,
                                         gru_wu, gru_bu, gru_wr, gru_br, gru_wc, gru_bc,
                                         encOut,
                                         (l == 1) ? 1 : 0,
                                         dec_w0, dec_b0, dec_w1, dec_b1,
                                         dual_w0, dual_b0, dual_w1, dual_b1, pred, dualp);
    const float* t = encIn; encIn = encOut; encOut = (float*)t;
  }

  k_primal_dual<<<NROW / 4, 256, 0, stream>>>(nb_cols, nb_cnt, pred, dualp, dem,
                                              rowsum, col_cnt, col_rows, col_vals, out);
  k_flow<<<BB, 1024, 0, stream>>>(col_cnt, col_rows, col_vals, dem, rowsum, out);
}

// Round 9
// 547.692 us; speedup vs baseline: 1.3332x; 1.0258x over previous
//
#include <hip/hip_runtime.h>

#define BB 8
#define VV 1200
#define DD 64
#define KH 2     // hops
#define NH 4     // heads
#define CAP 64        // hop1 cap
#define NB2CAP 384    // hop2 cap
#define NROW (BB*VV)          // 9600
#define NKROW (KH*BB*VV)      // 19200

__device__ __forceinline__ float wredsum(float v) {
#pragma unroll
  for (int o = 32; o > 0; o >>= 1) v += __shfl_xor(v, o, 64);
  return v;
}
// reduce across 16 lanes sharing a row group
__device__ __forceinline__ float gredsum(float v) {
#pragma unroll
  for (int o = 8; o > 0; o >>= 1) v += __shfl_xor(v, o, 64);
  return v;
}

// fast tanh via hw exp: tanh(x) = 1 - 2/(e^{2x}+1)
__device__ __forceinline__ float tanh_f(float x) {
  float e = __expf(2.0f * x);
  return 1.0f - 2.0f / (e + 1.0f);
}
__device__ __forceinline__ float sigmoid_f(float x) { return 1.0f / (1.0f + __expf(-x)); }

__device__ __forceinline__ size_t nb_base(int row) {
  return (row < NROW) ? (size_t)row * CAP
                      : (size_t)NROW * CAP + (size_t)(row - NROW) * NB2CAP;
}

// ---------------- fused pre: nbcsr (blocks 0..4799) + encoder (4800..5999) + zero (6000) ----
__global__ void __launch_bounds__(256) k_pre(
    const float* __restrict__ nb, int* __restrict__ nb_cols, int* __restrict__ nb_cnt,
    const float* __restrict__ emb, const float* __restrict__ feat,
    const float* __restrict__ w0, const float* __restrict__ b0,
    const float* __restrict__ w1, const float* __restrict__ b1,
    float* __restrict__ enc0,
    int* __restrict__ col_cnt, float* __restrict__ out, int out_size) {
  __shared__ float xT[8][25];
  __shared__ float hT[8][65];
  const int nbBlocks = NKROW / 4;       // 4800
  const int encBlocks = NROW / 8;       // 1200
  int bid = blockIdx.x;
  int tid = threadIdx.x;
  if (bid < nbBlocks) {
    // ---- CSR build ----
    int wid = tid >> 6, lane = tid & 63;
    int row = bid * 4 + wid;
    const float* nbrow = nb + (size_t)row * VV;
    size_t base = nb_base(row);
    int cap = (row < NROW) ? CAP : NB2CAP;
    unsigned long long ltmask = (lane == 0) ? 0ull : ((1ull << lane) - 1ull);
    int cnt = 0;
    for (int b0_ = 0; b0_ < VV; b0_ += 64) {
      int v = b0_ + lane;
      float val = (v < VV) ? nbrow[v] : 0.0f;
      unsigned long long mask = __ballot(val != 0.0f);
      int off = cnt + __popcll(mask & ltmask);
      if (val != 0.0f && off < cap) nb_cols[base + off] = v;
      cnt += __popcll(mask);
    }
    if (lane == 0) nb_cnt[row] = (cnt > cap) ? cap : cnt;
  } else if (bid < nbBlocks + encBlocks) {
    // ---- encoder: 8 rows/block, thread=(row, col-pair) ----
    int tile0 = (bid - nbBlocks) * 8;
    if (tid < 128) { int i = tid >> 4, d = tid & 15; xT[i][d] = emb[(size_t)(tile0 + i) * 16 + d]; }
    else if (tid < 192) { int t = tid - 128; int i = t >> 3, d = t & 7; xT[i][16 + d] = feat[(size_t)(tile0 + i) * 8 + d]; }
    __syncthreads();
    int r = tid >> 5, cg = tid & 31;
    int c0 = cg * 2;
    float a0 = b0[c0], a1 = b0[c0 + 1];
#pragma unroll
    for (int kk = 0; kk < 24; ++kk) {
      float x = xT[r][kk];
      float2 w2 = *(const float2*)(w0 + kk * DD + c0);
      a0 = fmaf(x, w2.x, a0); a1 = fmaf(x, w2.y, a1);
    }
    hT[r][c0] = tanh_f(a0); hT[r][c0 + 1] = tanh_f(a1);
    __syncthreads();
    float g0 = b1[c0], g1 = b1[c0 + 1];
#pragma unroll 16
    for (int kk = 0; kk < DD; ++kk) {
      float x = hT[r][kk];
      float2 w2 = *(const float2*)(w1 + kk * DD + c0);
      g0 = fmaf(x, w2.x, g0); g1 = fmaf(x, w2.y, g1);
    }
    float2 o; o.x = tanh_f(g0); o.y = tanh_f(g1);
    *(float2*)(enc0 + (size_t)(tile0 + r) * DD + c0) = o;
  } else {
    // ---- zero col_cnt + out ----
    for (int i = tid; i < NROW; i += 256) col_cnt[i] = 0;
    if (tid < out_size) out[tid] = 0.0f;
  }
}

// ---------------- gather: wave per row, float4 lanes, col-prefetch pipeline ----------------
__global__ void __launch_bounds__(256) k_gather(
    const int* __restrict__ nb_cols, const int* __restrict__ nb_cnt,
    const float* __restrict__ encIn, float* __restrict__ msg) {
  int w = threadIdx.x >> 6, lane = threadIdx.x & 63;
  int row = blockIdx.x * 4 + w;           // [0, NKROW)
  int k = (row >= NROW) ? 1 : 0;
  int bv = row - k * NROW;
  int b = bv / VV;
  const float4* enc4 = (const float4*)(encIn + (size_t)b * VV * DD);
  const int* cols = nb_cols + nb_base(row);
  int n = nb_cnt[row];
  int sub = lane >> 4, q = lane & 15;
  float ax = 0.0f, ay = 0.0f, az = 0.0f, aw = 0.0f;
  int j = 0;
  int cc0 = 0, cc1 = 0, cc2 = 0, cc3 = 0;
  if (j + 16 <= n) {
    cc0 = cols[j + sub]; cc1 = cols[j + 4 + sub];
    cc2 = cols[j + 8 + sub]; cc3 = cols[j + 12 + sub];
  }
  while (j + 16 <= n) {
    int nj = j + 16;
    int p0 = 0, p1 = 0, p2 = 0, p3 = 0;
    if (nj + 16 <= n) {              // prefetch next chunk's cols
      p0 = cols[nj + sub]; p1 = cols[nj + 4 + sub];
      p2 = cols[nj + 8 + sub]; p3 = cols[nj + 12 + sub];
    }
    float4 v0 = enc4[(size_t)cc0 * 16 + q];
    float4 v1 = enc4[(size_t)cc1 * 16 + q];
    float4 v2 = enc4[(size_t)cc2 * 16 + q];
    float4 v3 = enc4[(size_t)cc3 * 16 + q];
    ax += (v0.x + v1.x) + (v2.x + v3.x);
    ay += (v0.y + v1.y) + (v2.y + v3.y);
    az += (v0.z + v1.z) + (v2.z + v3.z);
    aw += (v0.w + v1.w) + (v2.w + v3.w);
    cc0 = p0; cc1 = p1; cc2 = p2; cc3 = p3;
    j = nj;
  }
  for (; j < n; j += 4) {
    int idx = j + sub;
    if (idx < n) {
      float4 v = enc4[(size_t)cols[idx] * 16 + q];
      ax += v.x; ay += v.y; az += v.z; aw += v.w;
    }
  }
#pragma unroll
  for (int o = 16; o < 64; o <<= 1) {
    ax += __shfl_xor(ax, o, 64);
    ay += __shfl_xor(ay, o, 64);
    az += __shfl_xor(az, o, 64);
    aw += __shfl_xor(aw, o, 64);
  }
  if (lane < 16) {
    float inv = 1.0f / fmaxf((float)n, 1.0f);
    float4 r; r.x = ax * inv; r.y = ay * inv; r.z = az * inv; r.w = aw * inv;
    ((float4*)(msg + (size_t)row * DD))[q] = r;
  }
}

// ---------------- agg GEMM + attention scores: 64-row tile, 512 thr, 2x4 reg tile ----------
__global__ void __launch_bounds__(512) k_aggatt(
    const float* __restrict__ msg,
    const float* __restrict__ agg_w, const float* __restrict__ agg_b,
    const float* __restrict__ att_w, const float* __restrict__ att_b,
    const float* __restrict__ att_v,
    float* __restrict__ agg, float* __restrict__ scores) {
  __shared__ float M[64][65];
  __shared__ float G[64][65];
  int tid = threadIdx.x;
  int tile0 = blockIdx.x * 64;            // [0, NKROW)
  int k = (tile0 >= NROW) ? 1 : 0;
  int bv0 = tile0 - k * NROW;
  int rsub = tid >> 4, cg = tid & 15;     // rsub 0..31, cg 0..15
  int c0 = cg * 4;
  int r0 = rsub * 2;
#pragma unroll
  for (int rep = 0; rep < 2; ++rep) {
    int idx = rep * 512 + tid; int i = idx >> 4, d4 = idx & 15;
    float4 m4 = *(const float4*)(msg + (size_t)(tile0 + i) * DD + d4 * 4);
    M[i][d4 * 4] = m4.x; M[i][d4 * 4 + 1] = m4.y; M[i][d4 * 4 + 2] = m4.z; M[i][d4 * 4 + 3] = m4.w;
  }
  __syncthreads();
  const float* W = agg_w + (size_t)k * DD * DD;
  float acc[2][4];
#pragma unroll
  for (int i = 0; i < 2; ++i)
#pragma unroll
    for (int j = 0; j < 4; ++j) acc[i][j] = agg_b[k * DD + c0 + j];
#pragma unroll 4
  for (int kk = 0; kk < DD; ++kk) {
    float4 w4 = *(const float4*)(W + kk * DD + c0);
    float x0 = M[r0][kk], x1 = M[r0 + 1][kk];
    acc[0][0] = fmaf(x0, w4.x, acc[0][0]); acc[0][1] = fmaf(x0, w4.y, acc[0][1]);
    acc[0][2] = fmaf(x0, w4.z, acc[0][2]); acc[0][3] = fmaf(x0, w4.w, acc[0][3]);
    acc[1][0] = fmaf(x1, w4.x, acc[1][0]); acc[1][1] = fmaf(x1, w4.y, acc[1][1]);
    acc[1][2] = fmaf(x1, w4.z, acc[1][2]); acc[1][3] = fmaf(x1, w4.w, acc[1][3]);
  }
#pragma unroll
  for (int i = 0; i < 2; ++i) {
    float4 g4;
    g4.x = tanh_f(acc[i][0]); g4.y = tanh_f(acc[i][1]);
    g4.z = tanh_f(acc[i][2]); g4.w = tanh_f(acc[i][3]);
    G[r0 + i][c0] = g4.x; G[r0 + i][c0 + 1] = g4.y; G[r0 + i][c0 + 2] = g4.z; G[r0 + i][c0 + 3] = g4.w;
    *(float4*)(agg + (size_t)(tile0 + r0 + i) * DD + c0) = g4;
  }
  __syncthreads();
#pragma unroll
  for (int h = 0; h < NH; ++h) {
    const float* Wh = att_w + (size_t)h * DD * DD;
    float a2[2][4];
#pragma unroll
    for (int i = 0; i < 2; ++i)
#pragma unroll
      for (int j = 0; j < 4; ++j) a2[i][j] = att_b[h * DD + c0 + j];
#pragma unroll 4
    for (int kk = 0; kk < DD; ++kk) {
      float4 w4 = *(const float4*)(Wh + kk * DD + c0);
      float x0 = G[r0][kk], x1 = G[r0 + 1][kk];
      a2[0][0] = fmaf(x0, w4.x, a2[0][0]); a2[0][1] = fmaf(x0, w4.y, a2[0][1]);
      a2[0][2] = fmaf(x0, w4.z, a2[0][2]); a2[0][3] = fmaf(x0, w4.w, a2[0][3]);
      a2[1][0] = fmaf(x1, w4.x, a2[1][0]); a2[1][1] = fmaf(x1, w4.y, a2[1][1]);
      a2[1][2] = fmaf(x1, w4.z, a2[1][2]); a2[1][3] = fmaf(x1, w4.w, a2[1][3]);
    }
    float4 v4 = *(const float4*)(att_v + h * DD + c0);
#pragma unroll
    for (int i = 0; i < 2; ++i) {
      float p = tanh_f(a2[i][0]) * v4.x + tanh_f(a2[i][1]) * v4.y
              + tanh_f(a2[i][2]) * v4.z + tanh_f(a2[i][3]) * v4.w;
      p = gredsum(p);
      if (cg == 0) scores[(size_t)(h * KH + k) * NROW + bv0 + r0 + i] = p;
    }
  }
}

// ---------------- attention mix + GRU (+ fused decode): 64-row tile, 512 thr, 2x4 tile ----
__global__ void __launch_bounds__(512) k_gru(
    const float* __restrict__ encIn, const float* __restrict__ agg,
    const float* __restrict__ scores,
    const float* __restrict__ wu, const float* __restrict__ bu,
    const float* __restrict__ wr, const float* __restrict__ br,
    const float* __restrict__ wc, const float* __restrict__ bc,
    float* __restrict__ encOut,
    int do_decode,
    const float* __restrict__ dw0, const float* __restrict__ db0,
    const float* __restrict__ dw1, const float* __restrict__ db1,
    const float* __restrict__ uw0, const float* __restrict__ ub0,
    const float* __restrict__ uw1, const float* __restrict__ ub1,
    float* __restrict__ pred, float* __restrict__ dualp) {
  __shared__ float X[64][129];     // [row][0..63]=nxt, [64..127]=enc then r*enc
  __shared__ float EO[64][65];
  int tid = threadIdx.x;
  int tile0 = blockIdx.x * 64;
  int rsub = tid >> 4, cg = tid & 15;
  int c0 = cg * 4;
  int r0 = rsub * 2;
  // load + inline softmax-mix (redundant per 16 threads sharing row; broadcast loads)
#pragma unroll
  for (int rep = 0; rep < 2; ++rep) {
    int idx = rep * 512 + tid; int i = idx >> 4, d4 = idx & 15;
    int row = tile0 + i;
    float W0 = 0.0f, W1 = 0.0f;
#pragma unroll
    for (int h = 0; h < NH; ++h) {
      float s0 = scores[(size_t)(h * KH + 0) * NROW + row];
      float s1 = scores[(size_t)(h * KH + 1) * NROW + row];
      float m = fmaxf(s0, s1);
      float e0 = __expf(s0 - m), e1 = __expf(s1 - m);
      float inv = 1.0f / (e0 + e1);
      W0 += e0 * inv; W1 += e1 * inv;
    }
    W0 *= 0.25f; W1 *= 0.25f;
    float4 e4 = *(const float4*)(encIn + (size_t)row * DD + d4 * 4);
    float4 a0 = *(const float4*)(agg + (size_t)row * DD + d4 * 4);
    float4 a1 = *(const float4*)(agg + (size_t)(NROW + row) * DD + d4 * 4);
    X[i][d4 * 4]     = W0 * a0.x + W1 * a1.x;
    X[i][d4 * 4 + 1] = W0 * a0.y + W1 * a1.y;
    X[i][d4 * 4 + 2] = W0 * a0.z + W1 * a1.z;
    X[i][d4 * 4 + 3] = W0 * a0.w + W1 * a1.w;
    X[i][64 + d4 * 4]     = e4.x;
    X[i][64 + d4 * 4 + 1] = e4.y;
    X[i][64 + d4 * 4 + 2] = e4.z;
    X[i][64 + d4 * 4 + 3] = e4.w;
  }
  __syncthreads();
  // u, r gates over xs=[nxt|enc]
  float au[2][4], ar[2][4];
#pragma unroll
  for (int i = 0; i < 2; ++i)
#pragma unroll
    for (int j = 0; j < 4; ++j) { au[i][j] = bu[c0 + j]; ar[i][j] = br[c0 + j]; }
#pragma unroll 4
  for (int kk = 0; kk < 2 * DD; ++kk) {
    float4 u4 = *(const float4*)(wu + kk * DD + c0);
    float4 r4 = *(const float4*)(wr + kk * DD + c0);
    float x0 = X[r0][kk], x1 = X[r0 + 1][kk];
    au[0][0] = fmaf(x0, u4.x, au[0][0]); au[0][1] = fmaf(x0, u4.y, au[0][1]);
    au[0][2] = fmaf(x0, u4.z, au[0][2]); au[0][3] = fmaf(x0, u4.w, au[0][3]);
    au[1][0] = fmaf(x1, u4.x, au[1][0]); au[1][1] = fmaf(x1, u4.y, au[1][1]);
    au[1][2] = fmaf(x1, u4.z, au[1][2]); au[1][3] = fmaf(x1, u4.w, au[1][3]);
    ar[0][0] = fmaf(x0, r4.x, ar[0][0]); ar[0][1] = fmaf(x0, r4.y, ar[0][1]);
    ar[0][2] = fmaf(x0, r4.z, ar[0][2]); ar[0][3] = fmaf(x0, r4.w, ar[0][3]);
    ar[1][0] = fmaf(x1, r4.x, ar[1][0]); ar[1][1] = fmaf(x1, r4.y, ar[1][1]);
    ar[1][2] = fmaf(x1, r4.z, ar[1][2]); ar[1][3] = fmaf(x1, r4.w, ar[1][3]);
  }
  float uu[2][4], encv[2][4];
#pragma unroll
  for (int i = 0; i < 2; ++i)
#pragma unroll
    for (int j = 0; j < 4; ++j) {
      uu[i][j] = sigmoid_f(au[i][j]);
      encv[i][j] = X[r0 + i][64 + c0 + j];
    }
  __syncthreads();    // all gate-pass reads of X done
#pragma unroll
  for (int i = 0; i < 2; ++i)
#pragma unroll
    for (int j = 0; j < 4; ++j)
      X[r0 + i][64 + c0 + j] = encv[i][j] * sigmoid_f(ar[i][j]);
  __syncthreads();
  // candidate
  float ac[2][4];
#pragma unroll
  for (int i = 0; i < 2; ++i)
#pragma unroll
    for (int j = 0; j < 4; ++j) ac[i][j] = bc[c0 + j];
#pragma unroll 4
  for (int kk = 0; kk < 2 * DD; ++kk) {
    float4 c4 = *(const float4*)(wc + kk * DD + c0);
    float x0 = X[r0][kk], x1 = X[r0 + 1][kk];
    ac[0][0] = fmaf(x0, c4.x, ac[0][0]); ac[0][1] = fmaf(x0, c4.y, ac[0][1]);
    ac[0][2] = fmaf(x0, c4.z, ac[0][2]); ac[0][3] = fmaf(x0, c4.w, ac[0][3]);
    ac[1][0] = fmaf(x1, c4.x, ac[1][0]); ac[1][1] = fmaf(x1, c4.y, ac[1][1]);
    ac[1][2] = fmaf(x1, c4.z, ac[1][2]); ac[1][3] = fmaf(x1, c4.w, ac[1][3]);
  }
#pragma unroll
  for (int i = 0; i < 2; ++i) {
    float4 e4;
    e4.x = uu[i][0] * encv[i][0] + (1.0f - uu[i][0]) * tanh_f(ac[i][0]);
    e4.y = uu[i][1] * encv[i][1] + (1.0f - uu[i][1]) * tanh_f(ac[i][1]);
    e4.z = uu[i][2] * encv[i][2] + (1.0f - uu[i][2]) * tanh_f(ac[i][2]);
    e4.w = uu[i][3] * encv[i][3] + (1.0f - uu[i][3]) * tanh_f(ac[i][3]);
    *(float4*)(encOut + (size_t)(tile0 + r0 + i) * DD + c0) = e4;
    EO[r0 + i][c0] = e4.x; EO[r0 + i][c0 + 1] = e4.y;
    EO[r0 + i][c0 + 2] = e4.z; EO[r0 + i][c0 + 3] = e4.w;
  }
  if (do_decode) {
    __syncthreads();
    float hd[2][4], hq[2][4];
#pragma unroll
    for (int i = 0; i < 2; ++i)
#pragma unroll
      for (int j = 0; j < 4; ++j) { hd[i][j] = db0[c0 + j]; hq[i][j] = ub0[c0 + j]; }
#pragma unroll 4
    for (int kk = 0; kk < DD; ++kk) {
      float4 d4 = *(const float4*)(dw0 + kk * DD + c0);
      float4 q4 = *(const float4*)(uw0 + kk * DD + c0);
      float x0 = EO[r0][kk], x1 = EO[r0 + 1][kk];
      hd[0][0] = fmaf(x0, d4.x, hd[0][0]); hd[0][1] = fmaf(x0, d4.y, hd[0][1]);
      hd[0][2] = fmaf(x0, d4.z, hd[0][2]); hd[0][3] = fmaf(x0, d4.w, hd[0][3]);
      hd[1][0] = fmaf(x1, d4.x, hd[1][0]); hd[1][1] = fmaf(x1, d4.y, hd[1][1]);
      hd[1][2] = fmaf(x1, d4.z, hd[1][2]); hd[1][3] = fmaf(x1, d4.w, hd[1][3]);
      hq[0][0] = fmaf(x0, q4.x, hq[0][0]); hq[0][1] = fmaf(x0, q4.y, hq[0][1]);
      hq[0][2] = fmaf(x0, q4.z, hq[0][2]); hq[0][3] = fmaf(x0, q4.w, hq[0][3]);
      hq[1][0] = fmaf(x1, q4.x, hq[1][0]); hq[1][1] = fmaf(x1, q4.y, hq[1][1]);
      hq[1][2] = fmaf(x1, q4.z, hq[1][2]); hq[1][3] = fmaf(x1, q4.w, hq[1][3]);
    }
    float4 dv = *(const float4*)(dw1 + c0);
    float4 qv = *(const float4*)(uw1 + c0);
#pragma unroll
    for (int i = 0; i < 2; ++i) {
      float p = hd[i][0] * dv.x + hd[i][1] * dv.y + hd[i][2] * dv.z + hd[i][3] * dv.w;
      float q = hq[i][0] * qv.x + hq[i][1] * qv.y + hq[i][2] * qv.z + hq[i][3] * qv.w;
      p = gredsum(p);
      q = gredsum(q);
      if (cg == 0) {
        pred[tile0 + r0 + i] = p + db1[0];
        dualp[tile0 + r0 + i] = q + ub1[0];
      }
    }
  }
}

// ------- fused: sparsemax (fixed-point tau) + CSC scatter + dual edge cost -------
__global__ void __launch_bounds__(256) k_primal_dual(
    const int* __restrict__ nb_cols, const int* __restrict__ nb_cnt,
    const float* __restrict__ pred, const float* __restrict__ dualp,
    const float* __restrict__ dem,
    float* __restrict__ rowsum,
    int* __restrict__ col_cnt, int* __restrict__ col_rows, float* __restrict__ col_vals,
    float* __restrict__ out) {
  __shared__ float bacc[BB];
  if (threadIdx.x < BB) bacc[threadIdx.x] = 0.0f;
  __syncthreads();
  int w = threadIdx.x >> 6, lane = threadIdx.x & 63;
  int row = blockIdx.x * 4 + w;
  int b = row / VV;
  int n = nb_cnt[row];
  int c = (lane < n) ? nb_cols[(size_t)row * CAP + lane] : 0;
  const float* predB = pred + (size_t)b * VV;
  const float* dualB = dualp + (size_t)b * VV;
  float z = (lane < n) ? predB[c] : -1e30f;
  float tau = 0.0f;
  if (n > 0) {
    bool in = (lane < n);
    for (int it = 0; it < 64; ++it) {
      float s = wredsum(in ? z : 0.0f);
      int cnt = (int)__popcll(__ballot(in));
      tau = (s - 1.0f) / (float)cnt;
      bool nin = (z > tau);
      if (__ballot(nin) == __ballot(in)) break;
      in = nin;
    }
  }
  float pv = (lane < n) ? fmaxf(z - tau, 0.0f) : 0.0f;
  float s2 = wredsum(pv * pv);
  if (lane == 0) rowsum[row] = s2;
  if (pv > 0.0f) {
    int g = b * VV + c;
    int j = atomicAdd(&col_cnt[g], 1);
    if (j < CAP) {
      col_rows[(size_t)g * CAP + j] = row - b * VV;
      col_vals[(size_t)g * CAP + j] = pv;
    }
  }
  float du = dualp[row];
  float es = 0.0f;
  if (lane < n) {
    float dd = du - dualB[c];
    float f = 0.0f, acm = 0.0f;
#pragma unroll
    for (int t = 0; t < 8; ++t) {
      float look = f - 0.9f * acm;
      float grad = 2.0f * look - dd;
      acm = 0.9f * acm + 0.1f * grad;
      f = fmaxf(f - acm, 0.0f);
    }
    es = f * f - dd * f;
  }
  float contrib = -es;
  if (lane == 0) contrib += du * dem[row];
  float ws_ = wredsum(contrib);
  if (lane == 0) atomicAdd(&bacc[b], ws_);
  __syncthreads();
  if (threadIdx.x < BB) {
    float t = bacc[threadIdx.x];
    if (t != 0.0f) atomicAdd(&out[threadIdx.x], t);
  }
}

// ------- fused flow iterations (per-graph block) + flow cost -------
__global__ void __launch_bounds__(1024) k_flow(
    const int* __restrict__ col_cnt, const int* __restrict__ col_rows,
    const float* __restrict__ col_vals, const float* __restrict__ dem,
    const float* __restrict__ rowsum, float* __restrict__ out) {
  __shared__ float aS[VV];
  __shared__ float red[16];
  int b = blockIdx.x;
  int tid = threadIdx.x;
  const float* demB = dem + (size_t)b * VV;
  for (int v = tid; v < VV; v += 1024) aS[v] = fmaxf(-demB[v], 0.0f);
  __syncthreads();
  for (int t = 0; t < 7; ++t) {
    float nv0 = 0.0f, nv1 = 0.0f;
    {
      int v = tid;
      if (v < VV) {
        int g = b * VV + v;
        int n = col_cnt[g]; if (n > CAP) n = CAP;
        const int* cr = col_rows + (size_t)g * CAP;
        const float* cv = col_vals + (size_t)g * CAP;
        float acc = 0.0f;
        for (int j = 0; j < n; ++j) acc += cv[j] * aS[cr[j]];
        nv0 = fmaxf(acc - demB[v], 0.0f);
      }
      v = tid + 1024;
      if (v < VV) {
        int g = b * VV + v;
        int n = col_cnt[g]; if (n > CAP) n = CAP;
        const int* cr = col_rows + (size_t)g * CAP;
        const float* cv = col_vals + (size_t)g * CAP;
        float acc = 0.0f;
        for (int j = 0; j < n; ++j) acc += cv[j] * aS[cr[j]];
        nv1 = fmaxf(acc - demB[v], 0.0f);
      }
    }
    __syncthreads();
    if (tid < VV) aS[tid] = nv0;
    if (tid + 1024 < VV) aS[tid + 1024] = nv1;
    __syncthreads();
  }
  float fc = 0.0f;
  for (int v = tid; v < VV; v += 1024) { float a = aS[v]; fc += a * a * rowsum[b * VV + v]; }
  fc = wredsum(fc);
  int wid = tid >> 6, lane = tid & 63;
  if (lane == 0) red[wid] = fc;
  __syncthreads();
  if (tid == 0) {
    float s = 0.0f;
#pragma unroll
    for (int i = 0; i < 16; ++i) s += red[i];
    atomicAdd(&out[b], s);
  }
}

extern "C" void kernel_launch(void* const* d_in, const int* in_sizes, int n_in,
                              void* d_out, int out_size, void* d_ws, size_t ws_size,
                              hipStream_t stream) {
  const float* feat   = (const float*)d_in[0];
  const float* emb    = (const float*)d_in[1];
  const float* dem    = (const float*)d_in[2];
  const float* nb     = (const float*)d_in[4];   // [K,B,V,V]
  const float* enc_w0 = (const float*)d_in[5];
  const float* enc_b0 = (const float*)d_in[6];
  const float* enc_w1 = (const float*)d_in[7];
  const float* enc_b1 = (const float*)d_in[8];
  const float* agg_w  = (const float*)d_in[9];
  const float* agg_b  = (const float*)d_in[10];
  const float* att_w  = (const float*)d_in[11];
  const float* att_b  = (const float*)d_in[12];
  const float* att_v  = (const float*)d_in[13];
  const float* gru_wu = (const float*)d_in[14];
  const float* gru_bu = (const float*)d_in[15];
  const float* gru_wr = (const float*)d_in[16];
  const float* gru_br = (const float*)d_in[17];
  const float* gru_wc = (const float*)d_in[18];
  const float* gru_bc = (const float*)d_in[19];
  const float* dec_w0 = (const float*)d_in[20];
  const float* dec_b0 = (const float*)d_in[21];
  const float* dec_w1 = (const float*)d_in[22];
  const float* dec_b1 = (const float*)d_in[23];
  const float* dual_w0= (const float*)d_in[24];
  const float* dual_b0= (const float*)d_in[25];
  const float* dual_w1= (const float*)d_in[26];
  const float* dual_b1= (const float*)d_in[27];
  float* out = (float*)d_out;

  float* ws = (float*)d_ws;
  float* enc0     = ws;                              // NROW*DD
  float* enc1     = enc0 + (size_t)NROW * DD;
  float* msg      = enc1 + (size_t)NROW * DD;        // NKROW*DD
  float* aggbuf   = msg + (size_t)NKROW * DD;        // NKROW*DD
  float* scores   = aggbuf + (size_t)NKROW * DD;     // NH*KH*NROW
  float* pred     = scores + (size_t)NH * KH * NROW;
  float* dualp    = pred + NROW;
  float* rowsum   = dualp + NROW;
  float* col_vals = rowsum + NROW;                   // NROW*CAP
  int* col_cnt  = (int*)(col_vals + (size_t)NROW * CAP);
  int* nb_cnt   = col_cnt + NROW;                    // NKROW
  int* col_rows = nb_cnt + NKROW;                    // NROW*CAP
  int* nb_cols  = col_rows + (size_t)NROW * CAP;

  (void)in_sizes; (void)n_in; (void)ws_size;

  // fused: CSR build + encoder + zero(col_cnt,out)
  k_pre<<<NKROW / 4 + NROW / 8 + 1, 256, 0, stream>>>(
      nb, nb_cols, nb_cnt, emb, feat, enc_w0, enc_b0, enc_w1, enc_b1, enc0,
      col_cnt, out, out_size);

  const float* encIn = enc0;
  float* encOut = enc1;
  for (int l = 0; l < 2; ++l) {
    k_gather<<<NKROW / 4, 256, 0, stream>>>(nb_cols, nb_cnt, encIn, msg);
    k_aggatt<<<NKROW / 64, 512, 0, stream>>>(msg, agg_w, agg_b, att_w, att_b, att_v,
                                             aggbuf, scores);
    k_gru<<<NROW / 64, 512, 0, stream>>>(encIn, aggbuf, scores,
                                         gru_wu, gru_bu, gru_wr, gru_br, gru_wc, gru_bc,
                                         encOut,
                                         (l == 1) ? 1 : 0,
                                         dec_w0, dec_b0, dec_w1, dec_b1,
                                         dual_w0, dual_b0, dual_w1, dual_b1, pred, dualp);
    const float* t = encIn; encIn = encOut; encOut = (float*)t;
  }

  k_primal_dual<<<NROW / 4, 256, 0, stream>>>(nb_cols, nb_cnt, pred, dualp, dem,
                                              rowsum, col_cnt, col_rows, col_vals, out);
  k_flow<<<BB, 1024, 0, stream>>>(col_cnt, col_rows, col_vals, dem, rowsum, out);
}

// Round 10
// 546.503 us; speedup vs baseline: 1.3361x; 1.0022x over previous
//
#include <hip/hip_runtime.h>

#define BB 8
#define VV 1200
#define DD 64
#define KH 2     // hops
#define NH 4     // heads
#define CAP 64        // hop1 cap
#define NB2CAP 384    // hop2 cap
#define NROW (BB*VV)          // 9600
#define NKROW (KH*BB*VV)      // 19200

__device__ __forceinline__ float wredsum(float v) {
#pragma unroll
  for (int o = 32; o > 0; o >>= 1) v += __shfl_xor(v, o, 64);
  return v;
}
__device__ __forceinline__ float gredsum(float v) {
#pragma unroll
  for (int o = 8; o > 0; o >>= 1) v += __shfl_xor(v, o, 64);
  return v;
}

__device__ __forceinline__ float tanh_f(float x) {
  float e = __expf(2.0f * x);
  return 1.0f - 2.0f / (e + 1.0f);
}
__device__ __forceinline__ float sigmoid_f(float x) { return 1.0f / (1.0f + __expf(-x)); }

// bf16 pack/unpack (RNE)
__device__ __forceinline__ unsigned pack_bf16x2(float a, float b) {
  unsigned ua = __float_as_uint(a), ub = __float_as_uint(b);
  ua = (ua + 0x7fffu + ((ua >> 16) & 1u)) >> 16;
  ub = (ub + 0x7fffu + ((ub >> 16) & 1u)) & 0xffff0000u;
  return ua | ub;
}
__device__ __forceinline__ float bf_lo(unsigned u) { return __uint_as_float(u << 16); }
__device__ __forceinline__ float bf_hi(unsigned u) { return __uint_as_float(u & 0xffff0000u); }

__device__ __forceinline__ size_t nb_base(int row) {
  return (row < NROW) ? (size_t)row * CAP
                      : (size_t)NROW * CAP + (size_t)(row - NROW) * NB2CAP;
}

// ---- fused pre: vectorized CSR build + encoder (bf16 out) + zero ----
__global__ void __launch_bounds__(256) k_pre(
    const float* __restrict__ nb, int* __restrict__ nb_cols, int* __restrict__ nb_cnt,
    const float* __restrict__ emb, const float* __restrict__ feat,
    const float* __restrict__ w0, const float* __restrict__ b0,
    const float* __restrict__ w1, const float* __restrict__ b1,
    unsigned* __restrict__ enc0,
    int* __restrict__ col_cnt, float* __restrict__ out, int out_size) {
  __shared__ float xT[8][25];
  __shared__ float hT[8][65];
  const int nbBlocks = NKROW / 4;       // 4800
  const int encBlocks = NROW / 8;       // 1200
  int bid = blockIdx.x;
  int tid = threadIdx.x;
  if (bid < nbBlocks) {
    int wid = tid >> 6, lane = tid & 63;
    int row = bid * 4 + wid;
    const float4* nb4 = (const float4*)(nb + (size_t)row * VV);
    size_t base = nb_base(row);
    int cap = (row < NROW) ? CAP : NB2CAP;
    unsigned long long ltmask = (lane == 0) ? 0ull : ((1ull << lane) - 1ull);
    int cnt = 0;
    for (int b0_ = 0; b0_ < VV; b0_ += 256) {
      int vi = b0_ + lane * 4;
      float4 v4 = {0.0f, 0.0f, 0.0f, 0.0f};
      if (vi < VV) v4 = nb4[(b0_ >> 2) + lane];
      int nz0 = (v4.x != 0.0f), nz1 = (v4.y != 0.0f), nz2 = (v4.z != 0.0f), nz3 = (v4.w != 0.0f);
      unsigned long long m0 = __ballot(nz0 != 0);
      unsigned long long m1 = __ballot(nz1 != 0);
      unsigned long long m2 = __ballot(nz2 != 0);
      unsigned long long m3 = __ballot(nz3 != 0);
      int off = cnt + __popcll(m0 & ltmask) + __popcll(m1 & ltmask)
                    + __popcll(m2 & ltmask) + __popcll(m3 & ltmask);
      if (nz0 && off < cap) nb_cols[base + off] = vi;
      off += nz0;
      if (nz1 && off < cap) nb_cols[base + off] = vi + 1;
      off += nz1;
      if (nz2 && off < cap) nb_cols[base + off] = vi + 2;
      off += nz2;
      if (nz3 && off < cap) nb_cols[base + off] = vi + 3;
      cnt += __popcll(m0) + __popcll(m1) + __popcll(m2) + __popcll(m3);
    }
    if (lane == 0) nb_cnt[row] = (cnt > cap) ? cap : cnt;
  } else if (bid < nbBlocks + encBlocks) {
    int tile0 = (bid - nbBlocks) * 8;
    if (tid < 128) { int i = tid >> 4, d = tid & 15; xT[i][d] = emb[(size_t)(tile0 + i) * 16 + d]; }
    else if (tid < 192) { int t = tid - 128; int i = t >> 3, d = t & 7; xT[i][16 + d] = feat[(size_t)(tile0 + i) * 8 + d]; }
    __syncthreads();
    int r = tid >> 5, cg = tid & 31;
    int c0 = cg * 2;
    float a0 = b0[c0], a1 = b0[c0 + 1];
#pragma unroll
    for (int kk = 0; kk < 24; ++kk) {
      float x = xT[r][kk];
      float2 w2 = *(const float2*)(w0 + kk * DD + c0);
      a0 = fmaf(x, w2.x, a0); a1 = fmaf(x, w2.y, a1);
    }
    hT[r][c0] = tanh_f(a0); hT[r][c0 + 1] = tanh_f(a1);
    __syncthreads();
    float g0 = b1[c0], g1 = b1[c0 + 1];
#pragma unroll 16
    for (int kk = 0; kk < DD; ++kk) {
      float x = hT[r][kk];
      float2 w2 = *(const float2*)(w1 + kk * DD + c0);
      g0 = fmaf(x, w2.x, g0); g1 = fmaf(x, w2.y, g1);
    }
    enc0[(size_t)(tile0 + r) * 32 + cg] = pack_bf16x2(tanh_f(g0), tanh_f(g1));
  } else {
    for (int i = tid; i < NROW; i += 256) col_cnt[i] = 0;
    if (tid < out_size) out[tid] = 0.0f;
  }
}

// ---- gather: wave per row, bf16 rows (uint2 per lane), col-prefetch pipeline ----
__global__ void __launch_bounds__(256) k_gather(
    const int* __restrict__ nb_cols, const int* __restrict__ nb_cnt,
    const unsigned* __restrict__ encIn, float* __restrict__ msg) {
  int w = threadIdx.x >> 6, lane = threadIdx.x & 63;
  int row = blockIdx.x * 4 + w;           // [0, NKROW)
  int k = (row >= NROW) ? 1 : 0;
  int bv = row - k * NROW;
  int b = bv / VV;
  const uint2* encU = (const uint2*)(encIn + (size_t)b * VV * 32);
  const int* cols = nb_cols + nb_base(row);
  int n = nb_cnt[row];
  int sub = lane >> 4, q = lane & 15;
  float ax = 0.0f, ay = 0.0f, az = 0.0f, aw = 0.0f;
  int j = 0;
  int cc0 = 0, cc1 = 0, cc2 = 0, cc3 = 0;
  if (j + 16 <= n) {
    cc0 = cols[j + sub]; cc1 = cols[j + 4 + sub];
    cc2 = cols[j + 8 + sub]; cc3 = cols[j + 12 + sub];
  }
  while (j + 16 <= n) {
    int nj = j + 16;
    int p0 = 0, p1 = 0, p2 = 0, p3 = 0;
    if (nj + 16 <= n) {
      p0 = cols[nj + sub]; p1 = cols[nj + 4 + sub];
      p2 = cols[nj + 8 + sub]; p3 = cols[nj + 12 + sub];
    }
    uint2 u0 = encU[(size_t)cc0 * 16 + q];
    uint2 u1 = encU[(size_t)cc1 * 16 + q];
    uint2 u2 = encU[(size_t)cc2 * 16 + q];
    uint2 u3 = encU[(size_t)cc3 * 16 + q];
    ax += (bf_lo(u0.x) + bf_lo(u1.x)) + (bf_lo(u2.x) + bf_lo(u3.x));
    ay += (bf_hi(u0.x) + bf_hi(u1.x)) + (bf_hi(u2.x) + bf_hi(u3.x));
    az += (bf_lo(u0.y) + bf_lo(u1.y)) + (bf_lo(u2.y) + bf_lo(u3.y));
    aw += (bf_hi(u0.y) + bf_hi(u1.y)) + (bf_hi(u2.y) + bf_hi(u3.y));
    cc0 = p0; cc1 = p1; cc2 = p2; cc3 = p3;
    j = nj;
  }
  for (; j < n; j += 4) {
    int idx = j + sub;
    if (idx < n) {
      uint2 u = encU[(size_t)cols[idx] * 16 + q];
      ax += bf_lo(u.x); ay += bf_hi(u.x); az += bf_lo(u.y); aw += bf_hi(u.y);
    }
  }
#pragma unroll
  for (int o = 16; o < 64; o <<= 1) {
    ax += __shfl_xor(ax, o, 64);
    ay += __shfl_xor(ay, o, 64);
    az += __shfl_xor(az, o, 64);
    aw += __shfl_xor(aw, o, 64);
  }
  if (lane < 16) {
    float inv = 1.0f / fmaxf((float)n, 1.0f);
    float4 r; r.x = ax * inv; r.y = ay * inv; r.z = az * inv; r.w = aw * inv;
    ((float4*)(msg + (size_t)row * DD))[q] = r;
  }
}

// ---- agg GEMM + attention scores: 64-row tile, 512 thr, 2x4 reg tile ----
__global__ void __launch_bounds__(512) k_aggatt(
    const float* __restrict__ msg,
    const float* __restrict__ agg_w, const float* __restrict__ agg_b,
    const float* __restrict__ att_w, const float* __restrict__ att_b,
    const float* __restrict__ att_v,
    float* __restrict__ agg, float* __restrict__ scores) {
  __shared__ float M[64][65];
  __shared__ float G[64][65];
  int tid = threadIdx.x;
  int tile0 = blockIdx.x * 64;            // [0, NKROW)
  int k = (tile0 >= NROW) ? 1 : 0;
  int bv0 = tile0 - k * NROW;
  int rsub = tid >> 4, cg = tid & 15;
  int c0 = cg * 4;
  int r0 = rsub * 2;
#pragma unroll
  for (int rep = 0; rep < 2; ++rep) {
    int idx = rep * 512 + tid; int i = idx >> 4, d4 = idx & 15;
    float4 m4 = *(const float4*)(msg + (size_t)(tile0 + i) * DD + d4 * 4);
    M[i][d4 * 4] = m4.x; M[i][d4 * 4 + 1] = m4.y; M[i][d4 * 4 + 2] = m4.z; M[i][d4 * 4 + 3] = m4.w;
  }
  __syncthreads();
  const float* W = agg_w + (size_t)k * DD * DD;
  float acc[2][4];
#pragma unroll
  for (int i = 0; i < 2; ++i)
#pragma unroll
    for (int j = 0; j < 4; ++j) acc[i][j] = agg_b[k * DD + c0 + j];
#pragma unroll 4
  for (int kk = 0; kk < DD; ++kk) {
    float4 w4 = *(const float4*)(W + kk * DD + c0);
    float x0 = M[r0][kk], x1 = M[r0 + 1][kk];
    acc[0][0] = fmaf(x0, w4.x, acc[0][0]); acc[0][1] = fmaf(x0, w4.y, acc[0][1]);
    acc[0][2] = fmaf(x0, w4.z, acc[0][2]); acc[0][3] = fmaf(x0, w4.w, acc[0][3]);
    acc[1][0] = fmaf(x1, w4.x, acc[1][0]); acc[1][1] = fmaf(x1, w4.y, acc[1][1]);
    acc[1][2] = fmaf(x1, w4.z, acc[1][2]); acc[1][3] = fmaf(x1, w4.w, acc[1][3]);
  }
#pragma unroll
  for (int i = 0; i < 2; ++i) {
    float4 g4;
    g4.x = tanh_f(acc[i][0]); g4.y = tanh_f(acc[i][1]);
    g4.z = tanh_f(acc[i][2]); g4.w = tanh_f(acc[i][3]);
    G[r0 + i][c0] = g4.x; G[r0 + i][c0 + 1] = g4.y; G[r0 + i][c0 + 2] = g4.z; G[r0 + i][c0 + 3] = g4.w;
    *(float4*)(agg + (size_t)(tile0 + r0 + i) * DD + c0) = g4;
  }
  __syncthreads();
#pragma unroll
  for (int h = 0; h < NH; ++h) {
    const float* Wh = att_w + (size_t)h * DD * DD;
    float a2[2][4];
#pragma unroll
    for (int i = 0; i < 2; ++i)
#pragma unroll
      for (int j = 0; j < 4; ++j) a2[i][j] = att_b[h * DD + c0 + j];
#pragma unroll 4
    for (int kk = 0; kk < DD; ++kk) {
      float4 w4 = *(const float4*)(Wh + kk * DD + c0);
      float x0 = G[r0][kk], x1 = G[r0 + 1][kk];
      a2[0][0] = fmaf(x0, w4.x, a2[0][0]); a2[0][1] = fmaf(x0, w4.y, a2[0][1]);
      a2[0][2] = fmaf(x0, w4.z, a2[0][2]); a2[0][3] = fmaf(x0, w4.w, a2[0][3]);
      a2[1][0] = fmaf(x1, w4.x, a2[1][0]); a2[1][1] = fmaf(x1, w4.y, a2[1][1]);
      a2[1][2] = fmaf(x1, w4.z, a2[1][2]); a2[1][3] = fmaf(x1, w4.w, a2[1][3]);
    }
    float4 v4 = *(const float4*)(att_v + h * DD + c0);
#pragma unroll
    for (int i = 0; i < 2; ++i) {
      float p = tanh_f(a2[i][0]) * v4.x + tanh_f(a2[i][1]) * v4.y
              + tanh_f(a2[i][2]) * v4.z + tanh_f(a2[i][3]) * v4.w;
      p = gredsum(p);
      if (cg == 0) scores[(size_t)(h * KH + k) * NROW + bv0 + r0 + i] = p;
    }
  }
}

// ---- attention mix + GRU (+ fused decode): bf16 enc state ----
__global__ void __launch_bounds__(512) k_gru(
    const unsigned* __restrict__ encIn, const float* __restrict__ agg,
    const float* __restrict__ scores,
    const float* __restrict__ wu, const float* __restrict__ bu,
    const float* __restrict__ wr, const float* __restrict__ br,
    const float* __restrict__ wc, const float* __restrict__ bc,
    unsigned* __restrict__ encOut,
    int do_decode,
    const float* __restrict__ dw0, const float* __restrict__ db0,
    const float* __restrict__ dw1, const float* __restrict__ db1,
    const float* __restrict__ uw0, const float* __restrict__ ub0,
    const float* __restrict__ uw1, const float* __restrict__ ub1,
    float* __restrict__ pred, float* __restrict__ dualp) {
  __shared__ float X[64][129];
  __shared__ float EO[64][65];
  int tid = threadIdx.x;
  int tile0 = blockIdx.x * 64;
  int rsub = tid >> 4, cg = tid & 15;
  int c0 = cg * 4;
  int r0 = rsub * 2;
#pragma unroll
  for (int rep = 0; rep < 2; ++rep) {
    int idx = rep * 512 + tid; int i = idx >> 4, d4 = idx & 15;
    int row = tile0 + i;
    float W0 = 0.0f, W1 = 0.0f;
#pragma unroll
    for (int h = 0; h < NH; ++h) {
      float s0 = scores[(size_t)(h * KH + 0) * NROW + row];
      float s1 = scores[(size_t)(h * KH + 1) * NROW + row];
      float m = fmaxf(s0, s1);
      float e0 = __expf(s0 - m), e1 = __expf(s1 - m);
      float inv = 1.0f / (e0 + e1);
      W0 += e0 * inv; W1 += e1 * inv;
    }
    W0 *= 0.25f; W1 *= 0.25f;
    uint2 eu = ((const uint2*)encIn)[(size_t)row * 16 + d4];
    float4 a0 = *(const float4*)(agg + (size_t)row * DD + d4 * 4);
    float4 a1 = *(const float4*)(agg + (size_t)(NROW + row) * DD + d4 * 4);
    X[i][d4 * 4]     = W0 * a0.x + W1 * a1.x;
    X[i][d4 * 4 + 1] = W0 * a0.y + W1 * a1.y;
    X[i][d4 * 4 + 2] = W0 * a0.z + W1 * a1.z;
    X[i][d4 * 4 + 3] = W0 * a0.w + W1 * a1.w;
    X[i][64 + d4 * 4]     = bf_lo(eu.x);
    X[i][64 + d4 * 4 + 1] = bf_hi(eu.x);
    X[i][64 + d4 * 4 + 2] = bf_lo(eu.y);
    X[i][64 + d4 * 4 + 3] = bf_hi(eu.y);
  }
  __syncthreads();
  float au[2][4], ar[2][4];
#pragma unroll
  for (int i = 0; i < 2; ++i)
#pragma unroll
    for (int j = 0; j < 4; ++j) { au[i][j] = bu[c0 + j]; ar[i][j] = br[c0 + j]; }
#pragma unroll 4
  for (int kk = 0; kk < 2 * DD; ++kk) {
    float4 u4 = *(const float4*)(wu + kk * DD + c0);
    float4 r4 = *(const float4*)(wr + kk * DD + c0);
    float x0 = X[r0][kk], x1 = X[r0 + 1][kk];
    au[0][0] = fmaf(x0, u4.x, au[0][0]); au[0][1] = fmaf(x0, u4.y, au[0][1]);
    au[0][2] = fmaf(x0, u4.z, au[0][2]); au[0][3] = fmaf(x0, u4.w, au[0][3]);
    au[1][0] = fmaf(x1, u4.x, au[1][0]); au[1][1] = fmaf(x1, u4.y, au[1][1]);
    au[1][2] = fmaf(x1, u4.z, au[1][2]); au[1][3] = fmaf(x1, u4.w, au[1][3]);
    ar[0][0] = fmaf(x0, r4.x, ar[0][0]); ar[0][1] = fmaf(x0, r4.y, ar[0][1]);
    ar[0][2] = fmaf(x0, r4.z, ar[0][2]); ar[0][3] = fmaf(x0, r4.w, ar[0][3]);
    ar[1][0] = fmaf(x1, r4.x, ar[1][0]); ar[1][1] = fmaf(x1, r4.y, ar[1][1]);
    ar[1][2] = fmaf(x1, r4.z, ar[1][2]); ar[1][3] = fmaf(x1, r4.w, ar[1][3]);
  }
  float uu[2][4], encv[2][4];
#pragma unroll
  for (int i = 0; i < 2; ++i)
#pragma unroll
    for (int j = 0; j < 4; ++j) {
      uu[i][j] = sigmoid_f(au[i][j]);
      encv[i][j] = X[r0 + i][64 + c0 + j];
    }
  __syncthreads();
#pragma unroll
  for (int i = 0; i < 2; ++i)
#pragma unroll
    for (int j = 0; j < 4; ++j)
      X[r0 + i][64 + c0 + j] = encv[i][j] * sigmoid_f(ar[i][j]);
  __syncthreads();
  float ac[2][4];
#pragma unroll
  for (int i = 0; i < 2; ++i)
#pragma unroll
    for (int j = 0; j < 4; ++j) ac[i][j] = bc[c0 + j];
#pragma unroll 4
  for (int kk = 0; kk < 2 * DD; ++kk) {
    float4 c4 = *(const float4*)(wc + kk * DD + c0);
    float x0 = X[r0][kk], x1 = X[r0 + 1][kk];
    ac[0][0] = fmaf(x0, c4.x, ac[0][0]); ac[0][1] = fmaf(x0, c4.y, ac[0][1]);
    ac[0][2] = fmaf(x0, c4.z, ac[0][2]); ac[0][3] = fmaf(x0, c4.w, ac[0][3]);
    ac[1][0] = fmaf(x1, c4.x, ac[1][0]); ac[1][1] = fmaf(x1, c4.y, ac[1][1]);
    ac[1][2] = fmaf(x1, c4.z, ac[1][2]); ac[1][3] = fmaf(x1, c4.w, ac[1][3]);
  }
#pragma unroll
  for (int i = 0; i < 2; ++i) {
    float4 e4;
    e4.x = uu[i][0] * encv[i][0] + (1.0f - uu[i][0]) * tanh_f(ac[i][0]);
    e4.y = uu[i][1] * encv[i][1] + (1.0f - uu[i][1]) * tanh_f(ac[i][1]);
    e4.z = uu[i][2] * encv[i][2] + (1.0f - uu[i][2]) * tanh_f(ac[i][2]);
    e4.w = uu[i][3] * encv[i][3] + (1.0f - uu[i][3]) * tanh_f(ac[i][3]);
    uint2 pk; pk.x = pack_bf16x2(e4.x, e4.y); pk.y = pack_bf16x2(e4.z, e4.w);
    ((uint2*)encOut)[(size_t)(tile0 + r0 + i) * 16 + cg] = pk;
    EO[r0 + i][c0] = e4.x; EO[r0 + i][c0 + 1] = e4.y;
    EO[r0 + i][c0 + 2] = e4.z; EO[r0 + i][c0 + 3] = e4.w;
  }
  if (do_decode) {
    __syncthreads();
    float hd[2][4], hq[2][4];
#pragma unroll
    for (int i = 0; i < 2; ++i)
#pragma unroll
      for (int j = 0; j < 4; ++j) { hd[i][j] = db0[c0 + j]; hq[i][j] = ub0[c0 + j]; }
#pragma unroll 4
    for (int kk = 0; kk < DD; ++kk) {
      float4 d4 = *(const float4*)(dw0 + kk * DD + c0);
      float4 q4 = *(const float4*)(uw0 + kk * DD + c0);
      float x0 = EO[r0][kk], x1 = EO[r0 + 1][kk];
      hd[0][0] = fmaf(x0, d4.x, hd[0][0]); hd[0][1] = fmaf(x0, d4.y, hd[0][1]);
      hd[0][2] = fmaf(x0, d4.z, hd[0][2]); hd[0][3] = fmaf(x0, d4.w, hd[0][3]);
      hd[1][0] = fmaf(x1, d4.x, hd[1][0]); hd[1][1] = fmaf(x1, d4.y, hd[1][1]);
      hd[1][2] = fmaf(x1, d4.z, hd[1][2]); hd[1][3] = fmaf(x1, d4.w, hd[1][3]);
      hq[0][0] = fmaf(x0, q4.x, hq[0][0]); hq[0][1] = fmaf(x0, q4.y, hq[0][1]);
      hq[0][2] = fmaf(x0, q4.z, hq[0][2]); hq[0][3] = fmaf(x0, q4.w, hq[0][3]);
      hq[1][0] = fmaf(x1, q4.x, hq[1][0]); hq[1][1] = fmaf(x1, q4.y, hq[1][1]);
      hq[1][2] = fmaf(x1, q4.z, hq[1][2]); hq[1][3] = fmaf(x1, q4.w, hq[1][3]);
    }
    float4 dv = *(const float4*)(dw1 + c0);
    float4 qv = *(const float4*)(uw1 + c0);
#pragma unroll
    for (int i = 0; i < 2; ++i) {
      float p = hd[i][0] * dv.x + hd[i][1] * dv.y + hd[i][2] * dv.z + hd[i][3] * dv.w;
      float q = hq[i][0] * qv.x + hq[i][1] * qv.y + hq[i][2] * qv.z + hq[i][3] * qv.w;
      p = gredsum(p);
      q = gredsum(q);
      if (cg == 0) {
        pred[tile0 + r0 + i] = p + db1[0];
        dualp[tile0 + r0 + i] = q + ub1[0];
      }
    }
  }
}

// ------- fused: sparsemax (fixed-point tau) + CSC scatter + dual edge cost -------
__global__ void __launch_bounds__(256) k_primal_dual(
    const int* __restrict__ nb_cols, const int* __restrict__ nb_cnt,
    const float* __restrict__ pred, const float* __restrict__ dualp,
    const float* __restrict__ dem,
    float* __restrict__ rowsum,
    int* __restrict__ col_cnt, int* __restrict__ col_rows, float* __restrict__ col_vals,
    float* __restrict__ out) {
  __shared__ float bacc[BB];
  if (threadIdx.x < BB) bacc[threadIdx.x] = 0.0f;
  __syncthreads();
  int w = threadIdx.x >> 6, lane = threadIdx.x & 63;
  int row = blockIdx.x * 4 + w;
  int b = row / VV;
  int n = nb_cnt[row];
  int c = (lane < n) ? nb_cols[(size_t)row * CAP + lane] : 0;
  const float* predB = pred + (size_t)b * VV;
  const float* dualB = dualp + (size_t)b * VV;
  float z = (lane < n) ? predB[c] : -1e30f;
  float tau = 0.0f;
  if (n > 0) {
    bool in = (lane < n);
    for (int it = 0; it < 64; ++it) {
      float s = wredsum(in ? z : 0.0f);
      int cnt = (int)__popcll(__ballot(in));
      tau = (s - 1.0f) / (float)cnt;
      bool nin = (z > tau);
      if (__ballot(nin) == __ballot(in)) break;
      in = nin;
    }
  }
  float pv = (lane < n) ? fmaxf(z - tau, 0.0f) : 0.0f;
  float s2 = wredsum(pv * pv);
  if (lane == 0) rowsum[row] = s2;
  if (pv > 0.0f) {
    int g = b * VV + c;
    int j = atomicAdd(&col_cnt[g], 1);
    if (j < CAP) {
      col_rows[(size_t)g * CAP + j] = row - b * VV;
      col_vals[(size_t)g * CAP + j] = pv;
    }
  }
  float du = dualp[row];
  float es = 0.0f;
  if (lane < n) {
    float dd = du - dualB[c];
    float f = 0.0f, acm = 0.0f;
#pragma unroll
    for (int t = 0; t < 8; ++t) {
      float look = f - 0.9f * acm;
      float grad = 2.0f * look - dd;
      acm = 0.9f * acm + 0.1f * grad;
      f = fmaxf(f - acm, 0.0f);
    }
    es = f * f - dd * f;
  }
  float contrib = -es;
  if (lane == 0) contrib += du * dem[row];
  float ws_ = wredsum(contrib);
  if (lane == 0) atomicAdd(&bacc[b], ws_);
  __syncthreads();
  if (threadIdx.x < BB) {
    float t = bacc[threadIdx.x];
    if (t != 0.0f) atomicAdd(&out[threadIdx.x], t);
  }
}

// ------- fused flow iterations (per-graph block) + flow cost -------
__global__ void __launch_bounds__(1024) k_flow(
    const int* __restrict__ col_cnt, const int* __restrict__ col_rows,
    const float* __restrict__ col_vals, const float* __restrict__ dem,
    const float* __restrict__ rowsum, float* __restrict__ out) {
  __shared__ float aS[VV];
  __shared__ float red[16];
  int b = blockIdx.x;
  int tid = threadIdx.x;
  const float* demB = dem + (size_t)b * VV;
  for (int v = tid; v < VV; v += 1024) aS[v] = fmaxf(-demB[v], 0.0f);
  __syncthreads();
  for (int t = 0; t < 7; ++t) {
    float nv0 = 0.0f, nv1 = 0.0f;
    {
      int v = tid;
      if (v < VV) {
        int g = b * VV + v;
        int n = col_cnt[g]; if (n > CAP) n = CAP;
        const int* cr = col_rows + (size_t)g * CAP;
        const float* cv = col_vals + (size_t)g * CAP;
        float acc = 0.0f;
        for (int j = 0; j < n; ++j) acc += cv[j] * aS[cr[j]];
        nv0 = fmaxf(acc - demB[v], 0.0f);
      }
      v = tid + 1024;
      if (v < VV) {
        int g = b * VV + v;
        int n = col_cnt[g]; if (n > CAP) n = CAP;
        const int* cr = col_rows + (size_t)g * CAP;
        const float* cv = col_vals + (size_t)g * CAP;
        float acc = 0.0f;
        for (int j = 0; j < n; ++j) acc += cv[j] * aS[cr[j]];
        nv1 = fmaxf(acc - demB[v], 0.0f);
      }
    }
    __syncthreads();
    if (tid < VV) aS[tid] = nv0;
    if (tid + 1024 < VV) aS[tid + 1024] = nv1;
    __syncthreads();
  }
  float fc = 0.0f;
  for (int v = tid; v < VV; v += 1024) { float a = aS[v]; fc += a * a * rowsum[b * VV + v]; }
  fc = wredsum(fc);
  int wid = tid >> 6, lane = tid & 63;
  if (lane == 0) red[wid] = fc;
  __syncthreads();
  if (tid == 0) {
    float s = 0.0f;
#pragma unroll
    for (int i = 0; i < 16; ++i) s += red[i];
    atomicAdd(&out[b], s);
  }
}

extern "C" void kernel_launch(void* const* d_in, const int* in_sizes, int n_in,
                              void* d_out, int out_size, void* d_ws, size_t ws_size,
                              hipStream_t stream) {
  const float* feat   = (const float*)d_in[0];
  const float* emb    = (const float*)d_in[1];
  const float* dem    = (const float*)d_in[2];
  const float* nb     = (const float*)d_in[4];   // [K,B,V,V]
  const float* enc_w0 = (const float*)d_in[5];
  const float* enc_b0 = (const float*)d_in[6];
  const float* enc_w1 = (const float*)d_in[7];
  const float* enc_b1 = (const float*)d_in[8];
  const float* agg_w  = (const float*)d_in[9];
  const float* agg_b  = (const float*)d_in[10];
  const float* att_w  = (const float*)d_in[11];
  const float* att_b  = (const float*)d_in[12];
  const float* att_v  = (const float*)d_in[13];
  const float* gru_wu = (const float*)d_in[14];
  const float* gru_bu = (const float*)d_in[15];
  const float* gru_wr = (const float*)d_in[16];
  const float* gru_br = (const float*)d_in[17];
  const float* gru_wc = (const float*)d_in[18];
  const float* gru_bc = (const float*)d_in[19];
  const float* dec_w0 = (const float*)d_in[20];
  const float* dec_b0 = (const float*)d_in[21];
  const float* dec_w1 = (const float*)d_in[22];
  const float* dec_b1 = (const float*)d_in[23];
  const float* dual_w0= (const float*)d_in[24];
  const float* dual_b0= (const float*)d_in[25];
  const float* dual_w1= (const float*)d_in[26];
  const float* dual_b1= (const float*)d_in[27];
  float* out = (float*)d_out;

  unsigned* enc0 = (unsigned*)d_ws;                      // NROW*32 uints (bf16x2)
  unsigned* enc1 = enc0 + (size_t)NROW * 32;
  float* msg      = (float*)(enc1 + (size_t)NROW * 32);  // NKROW*DD
  float* aggbuf   = msg + (size_t)NKROW * DD;            // NKROW*DD
  float* scores   = aggbuf + (size_t)NKROW * DD;         // NH*KH*NROW
  float* pred     = scores + (size_t)NH * KH * NROW;
  float* dualp    = pred + NROW;
  float* rowsum   = dualp + NROW;
  float* col_vals = rowsum + NROW;                       // NROW*CAP
  int* col_cnt  = (int*)(col_vals + (size_t)NROW * CAP);
  int* nb_cnt   = col_cnt + NROW;                        // NKROW
  int* col_rows = nb_cnt + NKROW;                        // NROW*CAP
  int* nb_cols  = col_rows + (size_t)NROW * CAP;

  (void)in_sizes; (void)n_in; (void)ws_size;

  k_pre<<<NKROW / 4 + NROW / 8 + 1, 256, 0, stream>>>(
      nb, nb_cols, nb_cnt, emb, feat, enc_w0, enc_b0, enc_w1, enc_b1, enc0,
      col_cnt, out, out_size);

  const unsigned* encIn = enc0;
  unsigned* encOut = enc1;
  for (int l = 0; l < 2; ++l) {
    k_gather<<<NKROW / 4, 256, 0, stream>>>(nb_cols, nb_cnt, encIn, msg);
    k_aggatt<<<NKROW / 64, 512, 0, stream>>>(msg, agg_w, agg_b, att_w, att_b, att_v,
                                             aggbuf, scores);
    k_gru<<<NROW / 64, 512, 0, stream>>>(encIn, aggbuf, scores,
                                         gru_wu, gru_bu, gru_wr, gru_br, gru_wc, gru_bc,
                                         encOut,
                                         (l == 1) ? 1 : 0,
                                         dec_w0, dec_b0, dec_w1, dec_b1,
                                         dual_w0, dual_b0, dual_w1, dual_b1, pred, dualp);
    const unsigned* t = encIn; encIn = encOut; encOut = (unsigned*)t;
  }

  k_primal_dual<<<NROW / 4, 256, 0, stream>>>(nb_cols, nb_cnt, pred, dualp, dem,
                                              rowsum, col_cnt, col_rows, col_vals, out);
  k_flow<<<BB, 1024, 0, stream>>>(col_cnt, col_rows, col_vals, dem, rowsum, out);
}

// Round 11
// 540.181 us; speedup vs baseline: 1.3518x; 1.0117x over previous
//
#include <hip/hip_runtime.h>

#define BB 8
#define VV 1200
#define DD 64
#define KH 2     // hops
#define NH 4     // heads
#define CAP 64        // hop1 cap
#define NB2CAP 384    // hop2 cap
#define NROW (BB*VV)          // 9600
#define NKROW (KH*BB*VV)      // 19200

__device__ __forceinline__ float wredsum(float v) {
#pragma unroll
  for (int o = 32; o > 0; o >>= 1) v += __shfl_xor(v, o, 64);
  return v;
}
__device__ __forceinline__ float gredsum(float v) {
#pragma unroll
  for (int o = 8; o > 0; o >>= 1) v += __shfl_xor(v, o, 64);
  return v;
}

__device__ __forceinline__ float tanh_f(float x) {
  float e = __expf(2.0f * x);
  return 1.0f - 2.0f / (e + 1.0f);
}
__device__ __forceinline__ float sigmoid_f(float x) { return 1.0f / (1.0f + __expf(-x)); }

// bf16 pack/unpack (RNE)
__device__ __forceinline__ unsigned pack_bf16x2(float a, float b) {
  unsigned ua = __float_as_uint(a), ub = __float_as_uint(b);
  ua = (ua + 0x7fffu + ((ua >> 16) & 1u)) >> 16;
  ub = (ub + 0x7fffu + ((ub >> 16) & 1u)) & 0xffff0000u;
  return ua | ub;
}
__device__ __forceinline__ float bf_lo(unsigned u) { return __uint_as_float(u << 16); }
__device__ __forceinline__ float bf_hi(unsigned u) { return __uint_as_float(u & 0xffff0000u); }

__device__ __forceinline__ size_t nb_base(int row) {
  return (row < NROW) ? (size_t)row * CAP
                      : (size_t)NROW * CAP + (size_t)(row - NROW) * NB2CAP;
}

// ---- fused pre (320 threads/block):
//   blocks [0, NKROW):                 CSR build, one ROW per block, 5 waves cover 5 chunks
//   blocks [NKROW, NKROW+NROW/8):      encoder (bf16 out), 8 rows/block
//   last block:                        zero col_cnt + out
__global__ void __launch_bounds__(320) k_pre(
    const float* __restrict__ nb, int* __restrict__ nb_cols, int* __restrict__ nb_cnt,
    const float* __restrict__ emb, const float* __restrict__ feat,
    const float* __restrict__ w0, const float* __restrict__ b0,
    const float* __restrict__ w1, const float* __restrict__ b1,
    unsigned* __restrict__ enc0,
    int* __restrict__ col_cnt, float* __restrict__ out, int out_size) {
  __shared__ float xT[8][25];
  __shared__ float hT[8][65];
  __shared__ int scnt[5];
  const int nbBlocks = NKROW;           // 19200
  const int encBlocks = NROW / 8;       // 1200
  int bid = blockIdx.x;
  int tid = threadIdx.x;
  if (bid < nbBlocks) {
    int w = tid >> 6, lane = tid & 63;
    int row = bid;
    const float4* nb4 = (const float4*)(nb + (size_t)row * VV);
    size_t base = nb_base(row);
    int cap = (row < NROW) ? CAP : NB2CAP;
    unsigned long long ltmask = (lane == 0) ? 0ull : ((1ull << lane) - 1ull);
    int idx4 = w * 64 + lane;           // float4 index; valid < 300 (VV/4)
    float4 v4 = {0.0f, 0.0f, 0.0f, 0.0f};
    if (idx4 < VV / 4) v4 = nb4[idx4];
    int nz0 = (v4.x != 0.0f), nz1 = (v4.y != 0.0f), nz2 = (v4.z != 0.0f), nz3 = (v4.w != 0.0f);
    unsigned long long m0 = __ballot(nz0 != 0);
    unsigned long long m1 = __ballot(nz1 != 0);
    unsigned long long m2 = __ballot(nz2 != 0);
    unsigned long long m3 = __ballot(nz3 != 0);
    int lanepref = __popcll(m0 & ltmask) + __popcll(m1 & ltmask)
                 + __popcll(m2 & ltmask) + __popcll(m3 & ltmask);
    int chunkcnt = __popcll(m0) + __popcll(m1) + __popcll(m2) + __popcll(m3);
    if (lane == 0) scnt[w] = chunkcnt;
    __syncthreads();
    int s0 = scnt[0], s1 = scnt[1], s2 = scnt[2], s3 = scnt[3], s4 = scnt[4];
    int baseoff = 0;
    if (w > 0) baseoff += s0;
    if (w > 1) baseoff += s1;
    if (w > 2) baseoff += s2;
    if (w > 3) baseoff += s3;
    int off = baseoff + lanepref;
    int vi = idx4 * 4;
    if (nz0 && off < cap) nb_cols[base + off] = vi;
    off += nz0;
    if (nz1 && off < cap) nb_cols[base + off] = vi + 1;
    off += nz1;
    if (nz2 && off < cap) nb_cols[base + off] = vi + 2;
    off += nz2;
    if (nz3 && off < cap) nb_cols[base + off] = vi + 3;
    if (tid == 0) {
      int total = s0 + s1 + s2 + s3 + s4;
      nb_cnt[row] = (total > cap) ? cap : total;
    }
  } else if (bid < nbBlocks + encBlocks) {
    int tile0 = (bid - nbBlocks) * 8;
    if (tid < 128) { int i = tid >> 4, d = tid & 15; xT[i][d] = emb[(size_t)(tile0 + i) * 16 + d]; }
    else if (tid < 192) { int t = tid - 128; int i = t >> 3, d = t & 7; xT[i][16 + d] = feat[(size_t)(tile0 + i) * 8 + d]; }
    __syncthreads();
    int r = tid >> 5, cg = tid & 31;
    int c0 = cg * 2;
    if (tid < 256) {
      float a0 = b0[c0], a1 = b0[c0 + 1];
#pragma unroll
      for (int kk = 0; kk < 24; ++kk) {
        float x = xT[r][kk];
        float2 w2 = *(const float2*)(w0 + kk * DD + c0);
        a0 = fmaf(x, w2.x, a0); a1 = fmaf(x, w2.y, a1);
      }
      hT[r][c0] = tanh_f(a0); hT[r][c0 + 1] = tanh_f(a1);
    }
    __syncthreads();
    if (tid < 256) {
      float g0 = b1[c0], g1 = b1[c0 + 1];
#pragma unroll 16
      for (int kk = 0; kk < DD; ++kk) {
        float x = hT[r][kk];
        float2 w2 = *(const float2*)(w1 + kk * DD + c0);
        g0 = fmaf(x, w2.x, g0); g1 = fmaf(x, w2.y, g1);
      }
      enc0[(size_t)(tile0 + r) * 32 + cg] = pack_bf16x2(tanh_f(g0), tanh_f(g1));
    }
  } else {
    for (int i = tid; i < NROW; i += 320) col_cnt[i] = 0;
    if (tid < out_size) out[tid] = 0.0f;
  }
}

// ---- gather: wave per row, bf16 rows (uint2 per lane), col-prefetch pipeline ----
__global__ void __launch_bounds__(256) k_gather(
    const int* __restrict__ nb_cols, const int* __restrict__ nb_cnt,
    const unsigned* __restrict__ encIn, float* __restrict__ msg) {
  int w = threadIdx.x >> 6, lane = threadIdx.x & 63;
  int row = blockIdx.x * 4 + w;           // [0, NKROW)
  int k = (row >= NROW) ? 1 : 0;
  int bv = row - k * NROW;
  int b = bv / VV;
  const uint2* encU = (const uint2*)(encIn + (size_t)b * VV * 32);
  const int* cols = nb_cols + nb_base(row);
  int n = nb_cnt[row];
  int sub = lane >> 4, q = lane & 15;
  float ax = 0.0f, ay = 0.0f, az = 0.0f, aw = 0.0f;
  int j = 0;
  int cc0 = 0, cc1 = 0, cc2 = 0, cc3 = 0;
  if (j + 16 <= n) {
    cc0 = cols[j + sub]; cc1 = cols[j + 4 + sub];
    cc2 = cols[j + 8 + sub]; cc3 = cols[j + 12 + sub];
  }
  while (j + 16 <= n) {
    int nj = j + 16;
    int p0 = 0, p1 = 0, p2 = 0, p3 = 0;
    if (nj + 16 <= n) {
      p0 = cols[nj + sub]; p1 = cols[nj + 4 + sub];
      p2 = cols[nj + 8 + sub]; p3 = cols[nj + 12 + sub];
    }
    uint2 u0 = encU[(size_t)cc0 * 16 + q];
    uint2 u1 = encU[(size_t)cc1 * 16 + q];
    uint2 u2 = encU[(size_t)cc2 * 16 + q];
    uint2 u3 = encU[(size_t)cc3 * 16 + q];
    ax += (bf_lo(u0.x) + bf_lo(u1.x)) + (bf_lo(u2.x) + bf_lo(u3.x));
    ay += (bf_hi(u0.x) + bf_hi(u1.x)) + (bf_hi(u2.x) + bf_hi(u3.x));
    az += (bf_lo(u0.y) + bf_lo(u1.y)) + (bf_lo(u2.y) + bf_lo(u3.y));
    aw += (bf_hi(u0.y) + bf_hi(u1.y)) + (bf_hi(u2.y) + bf_hi(u3.y));
    cc0 = p0; cc1 = p1; cc2 = p2; cc3 = p3;
    j = nj;
  }
  for (; j < n; j += 4) {
    int idx = j + sub;
    if (idx < n) {
      uint2 u = encU[(size_t)cols[idx] * 16 + q];
      ax += bf_lo(u.x); ay += bf_hi(u.x); az += bf_lo(u.y); aw += bf_hi(u.y);
    }
  }
#pragma unroll
  for (int o = 16; o < 64; o <<= 1) {
    ax += __shfl_xor(ax, o, 64);
    ay += __shfl_xor(ay, o, 64);
    az += __shfl_xor(az, o, 64);
    aw += __shfl_xor(aw, o, 64);
  }
  if (lane < 16) {
    float inv = 1.0f / fmaxf((float)n, 1.0f);
    float4 r; r.x = ax * inv; r.y = ay * inv; r.z = az * inv; r.w = aw * inv;
    ((float4*)(msg + (size_t)row * DD))[q] = r;
  }
}

// ---- agg GEMM + attention scores: 64-row tile, 512 thr, 2x4 reg tile ----
__global__ void __launch_bounds__(512) k_aggatt(
    const float* __restrict__ msg,
    const float* __restrict__ agg_w, const float* __restrict__ agg_b,
    const float* __restrict__ att_w, const float* __restrict__ att_b,
    const float* __restrict__ att_v,
    float* __restrict__ agg, float* __restrict__ scores) {
  __shared__ float M[64][65];
  __shared__ float G[64][65];
  int tid = threadIdx.x;
  int tile0 = blockIdx.x * 64;            // [0, NKROW)
  int k = (tile0 >= NROW) ? 1 : 0;
  int bv0 = tile0 - k * NROW;
  int rsub = tid >> 4, cg = tid & 15;
  int c0 = cg * 4;
  int r0 = rsub * 2;
#pragma unroll
  for (int rep = 0; rep < 2; ++rep) {
    int idx = rep * 512 + tid; int i = idx >> 4, d4 = idx & 15;
    float4 m4 = *(const float4*)(msg + (size_t)(tile0 + i) * DD + d4 * 4);
    M[i][d4 * 4] = m4.x; M[i][d4 * 4 + 1] = m4.y; M[i][d4 * 4 + 2] = m4.z; M[i][d4 * 4 + 3] = m4.w;
  }
  __syncthreads();
  const float* W = agg_w + (size_t)k * DD * DD;
  float acc[2][4];
#pragma unroll
  for (int i = 0; i < 2; ++i)
#pragma unroll
    for (int j = 0; j < 4; ++j) acc[i][j] = agg_b[k * DD + c0 + j];
#pragma unroll 4
  for (int kk = 0; kk < DD; ++kk) {
    float4 w4 = *(const float4*)(W + kk * DD + c0);
    float x0 = M[r0][kk], x1 = M[r0 + 1][kk];
    acc[0][0] = fmaf(x0, w4.x, acc[0][0]); acc[0][1] = fmaf(x0, w4.y, acc[0][1]);
    acc[0][2] = fmaf(x0, w4.z, acc[0][2]); acc[0][3] = fmaf(x0, w4.w, acc[0][3]);
    acc[1][0] = fmaf(x1, w4.x, acc[1][0]); acc[1][1] = fmaf(x1, w4.y, acc[1][1]);
    acc[1][2] = fmaf(x1, w4.z, acc[1][2]); acc[1][3] = fmaf(x1, w4.w, acc[1][3]);
  }
#pragma unroll
  for (int i = 0; i < 2; ++i) {
    float4 g4;
    g4.x = tanh_f(acc[i][0]); g4.y = tanh_f(acc[i][1]);
    g4.z = tanh_f(acc[i][2]); g4.w = tanh_f(acc[i][3]);
    G[r0 + i][c0] = g4.x; G[r0 + i][c0 + 1] = g4.y; G[r0 + i][c0 + 2] = g4.z; G[r0 + i][c0 + 3] = g4.w;
    *(float4*)(agg + (size_t)(tile0 + r0 + i) * DD + c0) = g4;
  }
  __syncthreads();
#pragma unroll
  for (int h = 0; h < NH; ++h) {
    const float* Wh = att_w + (size_t)h * DD * DD;
    float a2[2][4];
#pragma unroll
    for (int i = 0; i < 2; ++i)
#pragma unroll
      for (int j = 0; j < 4; ++j) a2[i][j] = att_b[h * DD + c0 + j];
#pragma unroll 4
    for (int kk = 0; kk < DD; ++kk) {
      float4 w4 = *(const float4*)(Wh + kk * DD + c0);
      float x0 = G[r0][kk], x1 = G[r0 + 1][kk];
      a2[0][0] = fmaf(x0, w4.x, a2[0][0]); a2[0][1] = fmaf(x0, w4.y, a2[0][1]);
      a2[0][2] = fmaf(x0, w4.z, a2[0][2]); a2[0][3] = fmaf(x0, w4.w, a2[0][3]);
      a2[1][0] = fmaf(x1, w4.x, a2[1][0]); a2[1][1] = fmaf(x1, w4.y, a2[1][1]);
      a2[1][2] = fmaf(x1, w4.z, a2[1][2]); a2[1][3] = fmaf(x1, w4.w, a2[1][3]);
    }
    float4 v4 = *(const float4*)(att_v + h * DD + c0);
#pragma unroll
    for (int i = 0; i < 2; ++i) {
      float p = tanh_f(a2[i][0]) * v4.x + tanh_f(a2[i][1]) * v4.y
              + tanh_f(a2[i][2]) * v4.z + tanh_f(a2[i][3]) * v4.w;
      p = gredsum(p);
      if (cg == 0) scores[(size_t)(h * KH + k) * NROW + bv0 + r0 + i] = p;
    }
  }
}

// ---- attention mix + GRU (+ fused decode): bf16 enc state ----
__global__ void __launch_bounds__(512) k_gru(
    const unsigned* __restrict__ encIn, const float* __restrict__ agg,
    const float* __restrict__ scores,
    const float* __restrict__ wu, const float* __restrict__ bu,
    const float* __restrict__ wr, const float* __restrict__ br,
    const float* __restrict__ wc, const float* __restrict__ bc,
    unsigned* __restrict__ encOut,
    int do_decode,
    const float* __restrict__ dw0, const float* __restrict__ db0,
    const float* __restrict__ dw1, const float* __restrict__ db1,
    const float* __restrict__ uw0, const float* __restrict__ ub0,
    const float* __restrict__ uw1, const float* __restrict__ ub1,
    float* __restrict__ pred, float* __restrict__ dualp) {
  __shared__ float X[64][129];
  __shared__ float EO[64][65];
  int tid = threadIdx.x;
  int tile0 = blockIdx.x * 64;
  int rsub = tid >> 4, cg = tid & 15;
  int c0 = cg * 4;
  int r0 = rsub * 2;
#pragma unroll
  for (int rep = 0; rep < 2; ++rep) {
    int idx = rep * 512 + tid; int i = idx >> 4, d4 = idx & 15;
    int row = tile0 + i;
    float W0 = 0.0f, W1 = 0.0f;
#pragma unroll
    for (int h = 0; h < NH; ++h) {
      float s0 = scores[(size_t)(h * KH + 0) * NROW + row];
      float s1 = scores[(size_t)(h * KH + 1) * NROW + row];
      float m = fmaxf(s0, s1);
      float e0 = __expf(s0 - m), e1 = __expf(s1 - m);
      float inv = 1.0f / (e0 + e1);
      W0 += e0 * inv; W1 += e1 * inv;
    }
    W0 *= 0.25f; W1 *= 0.25f;
    uint2 eu = ((const uint2*)encIn)[(size_t)row * 16 + d4];
    float4 a0 = *(const float4*)(agg + (size_t)row * DD + d4 * 4);
    float4 a1 = *(const float4*)(agg + (size_t)(NROW + row) * DD + d4 * 4);
    X[i][d4 * 4]     = W0 * a0.x + W1 * a1.x;
    X[i][d4 * 4 + 1] = W0 * a0.y + W1 * a1.y;
    X[i][d4 * 4 + 2] = W0 * a0.z + W1 * a1.z;
    X[i][d4 * 4 + 3] = W0 * a0.w + W1 * a1.w;
    X[i][64 + d4 * 4]     = bf_lo(eu.x);
    X[i][64 + d4 * 4 + 1] = bf_hi(eu.x);
    X[i][64 + d4 * 4 + 2] = bf_lo(eu.y);
    X[i][64 + d4 * 4 + 3] = bf_hi(eu.y);
  }
  __syncthreads();
  float au[2][4], ar[2][4];
#pragma unroll
  for (int i = 0; i < 2; ++i)
#pragma unroll
    for (int j = 0; j < 4; ++j) { au[i][j] = bu[c0 + j]; ar[i][j] = br[c0 + j]; }
#pragma unroll 4
  for (int kk = 0; kk < 2 * DD; ++kk) {
    float4 u4 = *(const float4*)(wu + kk * DD + c0);
    float4 r4 = *(const float4*)(wr + kk * DD + c0);
    float x0 = X[r0][kk], x1 = X[r0 + 1][kk];
    au[0][0] = fmaf(x0, u4.x, au[0][0]); au[0][1] = fmaf(x0, u4.y, au[0][1]);
    au[0][2] = fmaf(x0, u4.z, au[0][2]); au[0][3] = fmaf(x0, u4.w, au[0][3]);
    au[1][0] = fmaf(x1, u4.x, au[1][0]); au[1][1] = fmaf(x1, u4.y, au[1][1]);
    au[1][2] = fmaf(x1, u4.z, au[1][2]); au[1][3] = fmaf(x1, u4.w, au[1][3]);
    ar[0][0] = fmaf(x0, r4.x, ar[0][0]); ar[0][1] = fmaf(x0, r4.y, ar[0][1]);
    ar[0][2] = fmaf(x0, r4.z, ar[0][2]); ar[0][3] = fmaf(x0, r4.w, ar[0][3]);
    ar[1][0] = fmaf(x1, r4.x, ar[1][0]); ar[1][1] = fmaf(x1, r4.y, ar[1][1]);
    ar[1][2] = fmaf(x1, r4.z, ar[1][2]); ar[1][3] = fmaf(x1, r4.w, ar[1][3]);
  }
  float uu[2][4], encv[2][4];
#pragma unroll
  for (int i = 0; i < 2; ++i)
#pragma unroll
    for (int j = 0; j < 4; ++j) {
      uu[i][j] = sigmoid_f(au[i][j]);
      encv[i][j] = X[r0 + i][64 + c0 + j];
    }
  __syncthreads();
#pragma unroll
  for (int i = 0; i < 2; ++i)
#pragma unroll
    for (int j = 0; j < 4; ++j)
      X[r0 + i][64 + c0 + j] = encv[i][j] * sigmoid_f(ar[i][j]);
  __syncthreads();
  float ac[2][4];
#pragma unroll
  for (int i = 0; i < 2; ++i)
#pragma unroll
    for (int j = 0; j < 4; ++j) ac[i][j] = bc[c0 + j];
#pragma unroll 4
  for (int kk = 0; kk < 2 * DD; ++kk) {
    float4 c4 = *(const float4*)(wc + kk * DD + c0);
    float x0 = X[r0][kk], x1 = X[r0 + 1][kk];
    ac[0][0] = fmaf(x0, c4.x, ac[0][0]); ac[0][1] = fmaf(x0, c4.y, ac[0][1]);
    ac[0][2] = fmaf(x0, c4.z, ac[0][2]); ac[0][3] = fmaf(x0, c4.w, ac[0][3]);
    ac[1][0] = fmaf(x1, c4.x, ac[1][0]); ac[1][1] = fmaf(x1, c4.y, ac[1][1]);
    ac[1][2] = fmaf(x1, c4.z, ac[1][2]); ac[1][3] = fmaf(x1, c4.w, ac[1][3]);
  }
#pragma unroll
  for (int i = 0; i < 2; ++i) {
    float4 e4;
    e4.x = uu[i][0] * encv[i][0] + (1.0f - uu[i][0]) * tanh_f(ac[i][0]);
    e4.y = uu[i][1] * encv[i][1] + (1.0f - uu[i][1]) * tanh_f(ac[i][1]);
    e4.z = uu[i][2] * encv[i][2] + (1.0f - uu[i][2]) * tanh_f(ac[i][2]);
    e4.w = uu[i][3] * encv[i][3] + (1.0f - uu[i][3]) * tanh_f(ac[i][3]);
    uint2 pk; pk.x = pack_bf16x2(e4.x, e4.y); pk.y = pack_bf16x2(e4.z, e4.w);
    ((uint2*)encOut)[(size_t)(tile0 + r0 + i) * 16 + cg] = pk;
    EO[r0 + i][c0] = e4.x; EO[r0 + i][c0 + 1] = e4.y;
    EO[r0 + i][c0 + 2] = e4.z; EO[r0 + i][c0 + 3] = e4.w;
  }
  if (do_decode) {
    __syncthreads();
    float hd[2][4], hq[2][4];
#pragma unroll
    for (int i = 0; i < 2; ++i)
#pragma unroll
      for (int j = 0; j < 4; ++j) { hd[i][j] = db0[c0 + j]; hq[i][j] = ub0[c0 + j]; }
#pragma unroll 4
    for (int kk = 0; kk < DD; ++kk) {
      float4 d4 = *(const float4*)(dw0 + kk * DD + c0);
      float4 q4 = *(const float4*)(uw0 + kk * DD + c0);
      float x0 = EO[r0][kk], x1 = EO[r0 + 1][kk];
      hd[0][0] = fmaf(x0, d4.x, hd[0][0]); hd[0][1] = fmaf(x0, d4.y, hd[0][1]);
      hd[0][2] = fmaf(x0, d4.z, hd[0][2]); hd[0][3] = fmaf(x0, d4.w, hd[0][3]);
      hd[1][0] = fmaf(x1, d4.x, hd[1][0]); hd[1][1] = fmaf(x1, d4.y, hd[1][1]);
      hd[1][2] = fmaf(x1, d4.z, hd[1][2]); hd[1][3] = fmaf(x1, d4.w, hd[1][3]);
      hq[0][0] = fmaf(x0, q4.x, hq[0][0]); hq[0][1] = fmaf(x0, q4.y, hq[0][1]);
      hq[0][2] = fmaf(x0, q4.z, hq[0][2]); hq[0][3] = fmaf(x0, q4.w, hq[0][3]);
      hq[1][0] = fmaf(x1, q4.x, hq[1][0]); hq[1][1] = fmaf(x1, q4.y, hq[1][1]);
      hq[1][2] = fmaf(x1, q4.z, hq[1][2]); hq[1][3] = fmaf(x1, q4.w, hq[1][3]);
    }
    float4 dv = *(const float4*)(dw1 + c0);
    float4 qv = *(const float4*)(uw1 + c0);
#pragma unroll
    for (int i = 0; i < 2; ++i) {
      float p = hd[i][0] * dv.x + hd[i][1] * dv.y + hd[i][2] * dv.z + hd[i][3] * dv.w;
      float q = hq[i][0] * qv.x + hq[i][1] * qv.y + hq[i][2] * qv.z + hq[i][3] * qv.w;
      p = gredsum(p);
      q = gredsum(q);
      if (cg == 0) {
        pred[tile0 + r0 + i] = p + db1[0];
        dualp[tile0 + r0 + i] = q + ub1[0];
      }
    }
  }
}

// ------- fused: sparsemax (fixed-point tau) + CSC scatter + dual edge cost -------
__global__ void __launch_bounds__(256) k_primal_dual(
    const int* __restrict__ nb_cols, const int* __restrict__ nb_cnt,
    const float* __restrict__ pred, const float* __restrict__ dualp,
    const float* __restrict__ dem,
    float* __restrict__ rowsum,
    int* __restrict__ col_cnt, int* __restrict__ col_rows, float* __restrict__ col_vals,
    float* __restrict__ out) {
  __shared__ float bacc[BB];
  if (threadIdx.x < BB) bacc[threadIdx.x] = 0.0f;
  __syncthreads();
  int w = threadIdx.x >> 6, lane = threadIdx.x & 63;
  int row = blockIdx.x * 4 + w;
  int b = row / VV;
  int n = nb_cnt[row];
  int c = (lane < n) ? nb_cols[(size_t)row * CAP + lane] : 0;
  const float* predB = pred + (size_t)b * VV;
  const float* dualB = dualp + (size_t)b * VV;
  float z = (lane < n) ? predB[c] : -1e30f;
  float tau = 0.0f;
  if (n > 0) {
    bool in = (lane < n);
    for (int it = 0; it < 64; ++it) {
      float s = wredsum(in ? z : 0.0f);
      int cnt = (int)__popcll(__ballot(in));
      tau = (s - 1.0f) / (float)cnt;
      bool nin = (z > tau);
      if (__ballot(nin) == __ballot(in)) break;
      in = nin;
    }
  }
  float pv = (lane < n) ? fmaxf(z - tau, 0.0f) : 0.0f;
  float s2 = wredsum(pv * pv);
  if (lane == 0) rowsum[row] = s2;
  if (pv > 0.0f) {
    int g = b * VV + c;
    int j = atomicAdd(&col_cnt[g], 1);
    if (j < CAP) {
      col_rows[(size_t)g * CAP + j] = row - b * VV;
      col_vals[(size_t)g * CAP + j] = pv;
    }
  }
  float du = dualp[row];
  float es = 0.0f;
  if (lane < n) {
    float dd = du - dualB[c];
    float f = 0.0f, acm = 0.0f;
#pragma unroll
    for (int t = 0; t < 8; ++t) {
      float look = f - 0.9f * acm;
      float grad = 2.0f * look - dd;
      acm = 0.9f * acm + 0.1f * grad;
      f = fmaxf(f - acm, 0.0f);
    }
    es = f * f - dd * f;
  }
  float contrib = -es;
  if (lane == 0) contrib += du * dem[row];
  float ws_ = wredsum(contrib);
  if (lane == 0) atomicAdd(&bacc[b], ws_);
  __syncthreads();
  if (threadIdx.x < BB) {
    float t = bacc[threadIdx.x];
    if (t != 0.0f) atomicAdd(&out[threadIdx.x], t);
  }
}

// ------- fused flow iterations (per-graph block) + flow cost -------
__global__ void __launch_bounds__(1024) k_flow(
    const int* __restrict__ col_cnt, const int* __restrict__ col_rows,
    const float* __restrict__ col_vals, const float* __restrict__ dem,
    const float* __restrict__ rowsum, float* __restrict__ out) {
  __shared__ float aS[VV];
  __shared__ float red[16];
  int b = blockIdx.x;
  int tid = threadIdx.x;
  const float* demB = dem + (size_t)b * VV;
  for (int v = tid; v < VV; v += 1024) aS[v] = fmaxf(-demB[v], 0.0f);
  __syncthreads();
  for (int t = 0; t < 7; ++t) {
    float nv0 = 0.0f, nv1 = 0.0f;
    {
      int v = tid;
      if (v < VV) {
        int g = b * VV + v;
        int n = col_cnt[g]; if (n > CAP) n = CAP;
        const int* cr = col_rows + (size_t)g * CAP;
        const float* cv = col_vals + (size_t)g * CAP;
        float acc = 0.0f;
        for (int j = 0; j < n; ++j) acc += cv[j] * aS[cr[j]];
        nv0 = fmaxf(acc - demB[v], 0.0f);
      }
      v = tid + 1024;
      if (v < VV) {
        int g = b * VV + v;
        int n = col_cnt[g]; if (n > CAP) n = CAP;
        const int* cr = col_rows + (size_t)g * CAP;
        const float* cv = col_vals + (size_t)g * CAP;
        float acc = 0.0f;
        for (int j = 0; j < n; ++j) acc += cv[j] * aS[cr[j]];
        nv1 = fmaxf(acc - demB[v], 0.0f);
      }
    }
    __syncthreads();
    if (tid < VV) aS[tid] = nv0;
    if (tid + 1024 < VV) aS[tid + 1024] = nv1;
    __syncthreads();
  }
  float fc = 0.0f;
  for (int v = tid; v < VV; v += 1024) { float a = aS[v]; fc += a * a * rowsum[b * VV + v]; }
  fc = wredsum(fc);
  int wid = tid >> 6, lane = tid & 63;
  if (lane == 0) red[wid] = fc;
  __syncthreads();
  if (tid == 0) {
    float s = 0.0f;
#pragma unroll
    for (int i = 0; i < 16; ++i) s += red[i];
    atomicAdd(&out[b], s);
  }
}

extern "C" void kernel_launch(void* const* d_in, const int* in_sizes, int n_in,
                              void* d_out, int out_size, void* d_ws, size_t ws_size,
                              hipStream_t stream) {
  const float* feat   = (const float*)d_in[0];
  const float* emb    = (const float*)d_in[1];
  const float* dem    = (const float*)d_in[2];
  const float* nb     = (const float*)d_in[4];   // [K,B,V,V]
  const float* enc_w0 = (const float*)d_in[5];
  const float* enc_b0 = (const float*)d_in[6];
  const float* enc_w1 = (const float*)d_in[7];
  const float* enc_b1 = (const float*)d_in[8];
  const float* agg_w  = (const float*)d_in[9];
  const float* agg_b  = (const float*)d_in[10];
  const float* att_w  = (const float*)d_in[11];
  const float* att_b  = (const float*)d_in[12];
  const float* att_v  = (const float*)d_in[13];
  const float* gru_wu = (const float*)d_in[14];
  const float* gru_bu = (const float*)d_in[15];
  const float* gru_wr = (const float*)d_in[16];
  const float* gru_br = (const float*)d_in[17];
  const float* gru_wc = (const float*)d_in[18];
  const float* gru_bc = (const float*)d_in[19];
  const float* dec_w0 = (const float*)d_in[20];
  const float* dec_b0 = (const float*)d_in[21];
  const float* dec_w1 = (const float*)d_in[22];
  const float* dec_b1 = (const float*)d_in[23];
  const float* dual_w0= (const float*)d_in[24];
  const float* dual_b0= (const float*)d_in[25];
  const float* dual_w1= (const float*)d_in[26];
  const float* dual_b1= (const float*)d_in[27];
  float* out = (float*)d_out;

  unsigned* enc0 = (unsigned*)d_ws;                      // NROW*32 uints (bf16x2)
  unsigned* enc1 = enc0 + (size_t)NROW * 32;
  float* msg      = (float*)(enc1 + (size_t)NROW * 32);  // NKROW*DD
  float* aggbuf   = msg + (size_t)NKROW * DD;            // NKROW*DD
  float* scores   = aggbuf + (size_t)NKROW * DD;         // NH*KH*NROW
  float* pred     = scores + (size_t)NH * KH * NROW;
  float* dualp    = pred + NROW;
  float* rowsum   = dualp + NROW;
  float* col_vals = rowsum + NROW;                       // NROW*CAP
  int* col_cnt  = (int*)(col_vals + (size_t)NROW * CAP);
  int* nb_cnt   = col_cnt + NROW;                        // NKROW
  int* col_rows = nb_cnt + NKROW;                        // NROW*CAP
  int* nb_cols  = col_rows + (size_t)NROW * CAP;

  (void)in_sizes; (void)n_in; (void)ws_size;

  k_pre<<<NKROW + NROW / 8 + 1, 320, 0, stream>>>(
      nb, nb_cols, nb_cnt, emb, feat, enc_w0, enc_b0, enc_w1, enc_b1, enc0,
      col_cnt, out, out_size);

  const unsigned* encIn = enc0;
  unsigned* encOut = enc1;
  for (int l = 0; l < 2; ++l) {
    k_gather<<<NKROW / 4, 256, 0, stream>>>(nb_cols, nb_cnt, encIn, msg);
    k_aggatt<<<NKROW / 64, 512, 0, stream>>>(msg, agg_w, agg_b, att_w, att_b, att_v,
                                             aggbuf, scores);
    k_gru<<<NROW / 64, 512, 0, stream>>>(encIn, aggbuf, scores,
                                         gru_wu, gru_bu, gru_wr, gru_br, gru_wc, gru_bc,
                                         encOut,
                                         (l == 1) ? 1 : 0,
                                         dec_w0, dec_b0, dec_w1, dec_b1,
                                         dual_w0, dual_b0, dual_w1, dual_b1, pred, dualp);
    const unsigned* t = encIn; encIn = encOut; encOut = (unsigned*)t;
  }

  k_primal_dual<<<NROW / 4, 256, 0, stream>>>(nb_cols, nb_cnt, pred, dualp, dem,
                                              rowsum, col_cnt, col_rows, col_vals, out);
  k_flow<<<BB, 1024, 0, stream>>>(col_cnt, col_rows, col_vals, dem, rowsum, out);
}